// Round 2
// baseline (138.731 us; speedup 1.0000x reference)
//
#include <hip/hip_runtime.h>
#include <hip/hip_bf16.h>
#include <math.h>

#define LOG2PI_F 1.8378770664093453f

typedef __attribute__((ext_vector_type(8))) short bf16x8;
typedef __attribute__((ext_vector_type(4))) float f32x4;
typedef __attribute__((ext_vector_type(16))) float f32x16;

static __device__ inline short f2bf(float x) {
  __hip_bfloat16 h = __float2bfloat16(x);
  return *reinterpret_cast<short*>(&h);
}
// NOTE: do NOT hand-write v_cvt_pk_bf16_f32 here — inline asm on this
// critical path regressed (guide T12/m240: compiler schedules the scalar
// cast sequence better than a pinned asm op).
static __device__ inline unsigned pack2(float lo, float hi) {
  unsigned a = (unsigned)(unsigned short)f2bf(lo);
  unsigned b = (unsigned)(unsigned short)f2bf(hi);
  return a | (b << 16);
}
static __device__ inline f32x4 mfma16(bf16x8 a, bf16x8 b, f32x4 c) {
  return __builtin_amdgcn_mfma_f32_16x16x32_bf16(a, b, c, 0, 0, 0);
}
static __device__ inline f32x16 mfma32(bf16x8 a, bf16x8 b, f32x16 c) {
  return __builtin_amdgcn_mfma_f32_32x32x16_bf16(a, b, c, 0, 0, 0);
}

// ---------------- K0: WTbf[k'][k] = bf16(softmax_row_k(tl)[k']) -------------
__global__ __launch_bounds__(64) void mmm_w_kernel(
    const float* __restrict__ tl, short* __restrict__ WTbf) {
  int r = blockIdx.x, lane = threadIdx.x;
  float v = tl[r * 64 + lane];
  float mx = v;
  #pragma unroll
  for (int off = 1; off < 64; off <<= 1) mx = fmaxf(mx, __shfl_xor(mx, off));
  float e = expf(v - mx);
  float s = e;
  #pragma unroll
  for (int off = 1; off < 64; off <<= 1) s += __shfl_xor(s, off);
  WTbf[lane * 64 + r] = f2bf(e / s);
}

// ---------------- K1: prep Gt bf16 [512][256] + const_c[512] ----------------
__global__ __launch_bounds__(128) void mmm_prep_kernel(
    const float* __restrict__ means, const float* __restrict__ log_vars,
    const float* __restrict__ weight_logits,
    short* __restrict__ Gt, float* __restrict__ const_c) {
  int sm = blockIdx.x;
  int s = sm >> 3, m = sm & 7;
  int d = threadIdx.x;
  float lv = log_vars[sm * 128 + d];
  float iv = expf(-lv);
  float mu = means[sm * 128 + d];
  float miv = mu * iv;
  Gt[sm * 256 + d] = f2bf(miv);
  Gt[sm * 256 + 128 + d] = f2bf(-0.5f * iv);
  float v = mu * miv + lv;
  #pragma unroll
  for (int off = 1; off < 64; off <<= 1) v += __shfl_xor(v, off);
  __shared__ float red[2];
  if ((d & 63) == 0) red[d >> 6] = v;
  __syncthreads();
  if (d == 0) {
    float tot = red[0] + red[1];
    float wl[8];
    float mx = -3.4e38f;
    #pragma unroll
    for (int j = 0; j < 8; ++j) { wl[j] = weight_logits[s * 8 + j]; mx = fmaxf(mx, wl[j]); }
    float sum = 0.f;
    #pragma unroll
    for (int j = 0; j < 8; ++j) sum += expf(wl[j] - mx);
    float lmw = wl[m] - mx - logf(sum);
    const_c[sm] = -0.5f * (tot + 128.0f * LOG2PI_F) + lmw;
  }
}

// ---------------- K2: prep XeP bf16 packed [8 kb2][32768 bt][32 kk] ----------
__global__ __launch_bounds__(256) void mmm_prepxe_kernel(
    const float* __restrict__ X, short* __restrict__ XeP) {
  int q = blockIdx.x >> 7;
  int bt = ((blockIdx.x & 127) << 8) + threadIdx.x;
  const float4* src = (const float4*)(X + (size_t)bt * 128 + q * 32);
  float xv[32];
  #pragma unroll
  for (int i = 0; i < 8; ++i) {
    float4 v = src[i];
    xv[4 * i] = v.x; xv[4 * i + 1] = v.y; xv[4 * i + 2] = v.z; xv[4 * i + 3] = v.w;
  }
  size_t base1 = ((size_t)q * 32768 + bt) * 32;
  size_t base2 = ((size_t)(q + 4) * 32768 + bt) * 32;
  int bx = bt & 3;
  #pragma unroll
  for (int g = 0; g < 4; ++g) {
    bf16x8 t1, t2;
    #pragma unroll
    for (int j = 0; j < 8; ++j) {
      float x = xv[g * 8 + j];
      t1[j] = f2bf(x);
      t2[j] = f2bf(x * x);
    }
    int gs = (g ^ bx) * 8;
    *(bf16x8*)&XeP[base1 + gs] = t1;
    *(bf16x8*)&XeP[base2 + gs] = t2;
  }
}

// ---------------- K3: MFMA emission GEMM, C[sm=512][bt=64-tile] ------------
__global__ __launch_bounds__(512) void mmm_emis_kernel(
    const short* __restrict__ Gt, const short* __restrict__ XeP,
    const float* __restrict__ const_c,
    float* __restrict__ ehat, float* __restrict__ cmax) {
  __shared__ __align__(16) short Bt[16384];  // 32 KB
  __shared__ __align__(16) float ccs[512];
  __shared__ float wavemax[8][64];
  __shared__ float colmax[64];
  int tid = threadIdx.x;
  int w = tid >> 6, lane = tid & 63, lr = lane & 15, lg = lane >> 4;

  ccs[tid] = const_c[tid];

  bf16x8 gf[4][8];
  #pragma unroll
  for (int rt = 0; rt < 4; ++rt) {
    int row = w * 64 + rt * 16 + lr;
    #pragma unroll
    for (int kc = 0; kc < 8; ++kc)
      gf[rt][kc] = *(const bf16x8*)&Gt[row * 256 + kc * 32 + lg * 8];
  }

  uint4 sreg[4];
  {
    size_t bt0 = (size_t)blockIdx.x * 64;
    #pragma unroll
    for (int r = 0; r < 4; ++r) {
      int ofs = r * 8192 + tid * 16;
      int kb2 = ofs >> 12, rem = ofs & 4095;
      sreg[r] = *(const uint4*)((const char*)XeP + ((size_t)kb2 * 32768 + bt0) * 64 + rem);
    }
  }

  for (int it = 0; it < 2; ++it) {
    int bt0 = (blockIdx.x + it * 256) * 64;
    __syncthreads();
    #pragma unroll
    for (int r = 0; r < 4; ++r)
      *(uint4*)((char*)Bt + r * 8192 + tid * 16) = sreg[r];
    __syncthreads();
    if (it == 0) {
      size_t bt0n = ((size_t)blockIdx.x + 256) * 64;
      #pragma unroll
      for (int r = 0; r < 4; ++r) {
        int ofs = r * 8192 + tid * 16;
        int kb2 = ofs >> 12, rem = ofs & 4095;
        sreg[r] = *(const uint4*)((const char*)XeP + ((size_t)kb2 * 32768 + bt0n) * 64 + rem);
      }
    }

    f32x4 acc[4][4];
    #pragma unroll
    for (int rt = 0; rt < 4; ++rt)
      #pragma unroll
      for (int ct = 0; ct < 4; ++ct)
        acc[rt][ct] = (f32x4){0.f, 0.f, 0.f, 0.f};

    #pragma unroll
    for (int kc = 0; kc < 8; ++kc) {
      bf16x8 bfr[4];
      #pragma unroll
      for (int ct = 0; ct < 4; ++ct) {
        int btL = ct * 16 + lr;
        bfr[ct] = *(const bf16x8*)&Bt[kc * 2048 + btL * 32 + ((lg ^ (btL & 3)) * 8)];
      }
      #pragma unroll
      for (int rt = 0; rt < 4; ++rt)
        #pragma unroll
        for (int ct = 0; ct < 4; ++ct)
          acc[rt][ct] = mfma16(gf[rt][kc], bfr[ct], acc[rt][ct]);
    }

    float lse[4][4];
    #pragma unroll
    for (int rt = 0; rt < 4; ++rt) {
      f32x4 cc = *(f32x4*)&ccs[w * 64 + rt * 16 + lg * 4];
      #pragma unroll
      for (int ct = 0; ct < 4; ++ct) {
        f32x4 v = acc[rt][ct] + cc;
        float mx = fmaxf(fmaxf(v[0], v[1]), fmaxf(v[2], v[3]));
        mx = fmaxf(mx, __shfl_xor(mx, 16));
        float sum = expf(v[0] - mx) + expf(v[1] - mx) + expf(v[2] - mx) + expf(v[3] - mx);
        sum += __shfl_xor(sum, 16);
        lse[rt][ct] = mx + logf(sum);
      }
    }
    #pragma unroll
    for (int ct = 0; ct < 4; ++ct) {
      float cm = fmaxf(fmaxf(lse[0][ct], lse[1][ct]), fmaxf(lse[2][ct], lse[3][ct]));
      cm = fmaxf(cm, __shfl_xor(cm, 32));
      if (lg == 0) wavemax[w][ct * 16 + lr] = cm;
    }
    __syncthreads();
    if (w == 0) {
      float cm = wavemax[0][lane];
      #pragma unroll
      for (int ww = 1; ww < 8; ++ww) cm = fmaxf(cm, wavemax[ww][lane]);
      colmax[lane] = cm;
      cmax[(size_t)bt0 + lane] = cm;
    }
    __syncthreads();
    #pragma unroll
    for (int ct = 0; ct < 4; ++ct) {
      float cm = colmax[ct * 16 + lr];
      #pragma unroll
      for (int rt = 0; rt < 4; ++rt) {
        float v = expf(lse[rt][ct] - cm);
        if (!(lg & 1))
          ehat[((size_t)bt0 + ct * 16 + lr) * 64 + (w * 8 + rt * 2 + (lg >> 1))] = v;
      }
    }
  }
}

// ---------------- K4: per-chunk product, 32x32 MFMA + permlane32_swap -------
// 256 chunks x 16 steps: doubles resident waves (8->16/CU) vs 128x32 and
// halves each block's serial chain. Wave wv owns cols [wv*32, wv*32+32).
// Step: C' = diag(e) * W^T * C.  C->B redistribution = one permlane32_swap
// per (quad-pair, p). bf16 repack via compiler-scheduled pack2 (m240).
__global__ __launch_bounds__(128) void mmm_chunk_kernel(
    const short* __restrict__ WTbf, const float* __restrict__ ehat,
    const float* __restrict__ cmax, float* __restrict__ NT,
    float* __restrict__ aux) {
  int chunk = blockIdx.x, b = blockIdx.y;
  int tid = threadIdx.x;
  int wv = tid >> 6, lane = tid & 63;
  int l31 = lane & 31, hi = lane >> 5;

  // A = W^T: af[wi][kb], row = wi*32+l31, k = kb*16 + hi*8 + j
  bf16x8 af[2][4];
  #pragma unroll
  for (int wi = 0; wi < 2; ++wi)
    #pragma unroll
    for (int kb = 0; kb < 4; ++kb)
      af[wi][kb] = *(const bf16x8*)&WTbf[(wi * 32 + l31) * 64 + kb * 16 + hi * 8];

  // state: C0/C1 (N = I). reg r -> row (r&3)+8*(r>>2)+4*hi, col wv*32+l31
  f32x16 c0, c1;
  #pragma unroll
  for (int r = 0; r < 16; ++r) {
    int row = (r & 3) + 8 * (r >> 2) + 4 * hi;
    c0[r] = (wv == 0 && row == l31) ? 1.f : 0.f;
    c1[r] = (wv == 1 && row == l31) ? 1.f : 0.f;
  }

  int t0 = (chunk == 0) ? 1 : chunk * 16;
  int nsteps = (chunk == 0) ? 15 : 16;
  const float* eb = ehat + (size_t)b * 4096 * 64;

  // packed state: P[cm][q][p] = rows 32cm+8q+4hi+{2p,2p+1} at this col
  unsigned P[2][4][2];
  #pragma unroll
  for (int q = 0; q < 4; ++q)
    #pragma unroll
    for (int p = 0; p < 2; ++p) {
      P[0][q][p] = pack2(c0[4 * q + 2 * p], c0[4 * q + 2 * p + 1]);
      P[1][q][p] = pack2(c1[4 * q + 2 * p], c1[4 * q + 2 * p + 1]);
    }

  float logscale = 0.f;
  f32x4 ecur[2][4], enxt[2][4];
  #pragma unroll
  for (int cm = 0; cm < 2; ++cm)
    #pragma unroll
    for (int q = 0; q < 4; ++q)
      ecur[cm][q] = *(const f32x4*)&eb[(size_t)t0 * 64 + cm * 32 + q * 8 + hi * 4];

  for (int it = 0; it < nsteps; ++it) {
    if (it + 1 < nsteps) {
      #pragma unroll
      for (int cm = 0; cm < 2; ++cm)
        #pragma unroll
        for (int q = 0; q < 4; ++q)
          enxt[cm][q] = *(const f32x4*)&eb[(size_t)(t0 + it + 1) * 64 + cm * 32 + q * 8 + hi * 4];
    }

    // B[kb]: k = kb*16 + 8*hi + j. One swap per (p): low word from vsrc',
    // high word from vdst'.
    bf16x8 B[4];
    #pragma unroll
    for (int kb = 0; kb < 4; ++kb) {
      int cm = kb >> 1, kbl = kb & 1;
      int4 wrd;
      #pragma unroll
      for (int p = 0; p < 2; ++p) {
        unsigned avv = P[cm][2 * kbl + 1][p];
        unsigned bvv = P[cm][2 * kbl][p];
        asm("v_permlane32_swap_b32 %0, %1" : "+v"(avv), "+v"(bvv));
        if (p == 0) { wrd.x = (int)bvv; wrd.z = (int)avv; }
        else        { wrd.y = (int)bvv; wrd.w = (int)avv; }
      }
      B[kb] = *(bf16x8*)&wrd;
    }

    f32x16 d0, d1;
    #pragma unroll
    for (int r = 0; r < 16; ++r) { d0[r] = 0.f; d1[r] = 0.f; }
    #pragma unroll
    for (int kb = 0; kb < 4; ++kb) {
      d0 = mfma32(af[0][kb], B[kb], d0);
      d1 = mfma32(af[1][kb], B[kb], d1);
    }

    // e-scale rows: reg 4q+s -> row 32cm+8q+4hi+s
    #pragma unroll
    for (int q = 0; q < 4; ++q)
      #pragma unroll
      for (int s = 0; s < 4; ++s) {
        c0[4 * q + s] = d0[4 * q + s] * ecur[0][q][s];
        c1[4 * q + s] = d1[4 * q + s] * ecur[1][q][s];
      }

    if ((it & 7) == 7) {  // per-wave (32-col strip) rescale
      float m = 0.f;
      #pragma unroll
      for (int r = 0; r < 16; ++r) m = fmaxf(m, fmaxf(c0[r], c1[r]));
      #pragma unroll
      for (int off = 1; off < 64; off <<= 1) m = fmaxf(m, __shfl_xor(m, off));
      float inv = 1.0f / m;
      #pragma unroll
      for (int r = 0; r < 16; ++r) { c0[r] *= inv; c1[r] *= inv; }
      logscale += logf(m);
    }

    #pragma unroll
    for (int q = 0; q < 4; ++q)
      #pragma unroll
      for (int p = 0; p < 2; ++p) {
        P[0][q][p] = pack2(c0[4 * q + 2 * p], c0[4 * q + 2 * p + 1]);
        P[1][q][p] = pack2(c1[4 * q + 2 * p], c1[4 * q + 2 * p + 1]);
      }
    #pragma unroll
    for (int cm = 0; cm < 2; ++cm)
      #pragma unroll
      for (int q = 0; q < 4; ++q) ecur[cm][q] = enxt[cm][q];
  }

  // store N_c f32 row-major [row][col]
  float* No = NT + (((size_t)b * 256 + chunk) << 12);
  #pragma unroll
  for (int r = 0; r < 16; ++r) {
    int row = (r & 3) + 8 * (r >> 2) + 4 * hi;
    No[row * 64 + wv * 32 + l31] = c0[r];
    No[(32 + row) * 64 + wv * 32 + l31] = c1[r];
  }

  // aux[b][chunk][wv] = sum cmax + per-strip logscale (strip = 32 cols)
  float cs = (lane < nsteps) ? cmax[(size_t)b * 4096 + t0 + lane] : 0.f;
  #pragma unroll
  for (int off = 1; off < 64; off <<= 1) cs += __shfl_xor(cs, off);
  if (lane == 0) aux[(((size_t)b * 256 + chunk) << 1) + wv] = cs + logscale;
}

// ---------------- K5: merge 16 chunks -> group matrix (16 groups/batch) -----
// Q' = N_cc * Q; per-32-col-strip scales of N_cc folded into A (k = column).
__global__ __launch_bounds__(256) void mmm_merge_kernel(
    const float* __restrict__ NT, const float* __restrict__ aux,
    float* __restrict__ G2T, float* __restrict__ auxg) {
  int g = blockIdx.x, b = blockIdx.y;
  int tid = threadIdx.x;
  int w = tid >> 6, lane = tid & 63;
  int wi = w >> 1, wj = w & 1;
  int lr = lane & 15, lg = lane >> 4;

  __shared__ __align__(16) short L[2][4096];
  __shared__ float wmax[4];

  for (int idx = tid; idx < 4096; idx += 256) {
    int j = idx >> 6, k = idx & 63;
    L[0][idx ^ ((j & 7) << 3)] = (j == k) ? (short)0x3F80 : (short)0;
  }
  __syncthreads();

  int cbase = b * 256 + g * 16;

  float logscale = 0.f;
  int cur = 0;
  f32x4 acc[2][2];

  f32x4 apre[2][2][2];
  {
    const float* Mc = NT + ((size_t)cbase << 12);
    #pragma unroll
    for (int rt = 0; rt < 2; ++rt)
      #pragma unroll
      for (int kc = 0; kc < 2; ++kc) {
        const float* src = Mc + (wi * 32 + rt * 16 + lr) * 64 + kc * 32 + lg * 8;
        apre[rt][kc][0] = *(const f32x4*)src;
        apre[rt][kc][1] = *(const f32x4*)(src + 4);
      }
  }

  for (int cc = 0; cc < 16; ++cc) {
    f32x4 acur[2][2][2];
    #pragma unroll
    for (int rt = 0; rt < 2; ++rt)
      #pragma unroll
      for (int kc = 0; kc < 2; ++kc) {
        acur[rt][kc][0] = apre[rt][kc][0];
        acur[rt][kc][1] = apre[rt][kc][1];
      }
    if (cc < 15) {
      const float* Mc = NT + ((size_t)(cbase + cc + 1) << 12);
      #pragma unroll
      for (int rt = 0; rt < 2; ++rt)
        #pragma unroll
        for (int kc = 0; kc < 2; ++kc) {
          const float* src = Mc + (wi * 32 + rt * 16 + lr) * 64 + kc * 32 + lg * 8;
          apre[rt][kc][0] = *(const f32x4*)src;
          apre[rt][kc][1] = *(const f32x4*)(src + 4);
        }
    }

    // per-strip (32-col) scale factors of N_cc; contraction k = column
    float a0 = aux[((cbase + cc) << 1) + 0];
    float a1 = aux[((cbase + cc) << 1) + 1];
    float ref = fmaxf(a0, a1);
    float fk0 = expf(a0 - ref);
    float fk1 = expf(a1 - ref);
    logscale += ref;

    bf16x8 afr[2][2];
    #pragma unroll
    for (int rt = 0; rt < 2; ++rt)
      #pragma unroll
      for (int kc = 0; kc < 2; ++kc) {
        float fk = kc ? fk1 : fk0;
        bf16x8 f;
        #pragma unroll
        for (int u = 0; u < 4; ++u) {
          f[u] = f2bf(acur[rt][kc][0][u] * fk);
          f[4 + u] = f2bf(acur[rt][kc][1][u] * fk);
        }
        afr[rt][kc] = f;
      }

    bf16x8 bfr[2][2];
    #pragma unroll
    for (int ct = 0; ct < 2; ++ct) {
      int j = wj * 32 + ct * 16 + lr;
      int sw = (j & 7) << 3;
      #pragma unroll
      for (int kc = 0; kc < 2; ++kc)
        bfr[ct][kc] = *(const bf16x8*)&L[cur][(j * 64 + kc * 32 + lg * 8) ^ sw];
    }

    #pragma unroll
    for (int rt = 0; rt < 2; ++rt)
      #pragma unroll
      for (int ct = 0; ct < 2; ++ct) {
        f32x4 c = {0.f, 0.f, 0.f, 0.f};
        c = mfma16(afr[rt][0], bfr[ct][0], c);
        c = mfma16(afr[rt][1], bfr[ct][1], c);
        acc[rt][ct] = c;
      }

    float m = 0.f;
    #pragma unroll
    for (int rt = 0; rt < 2; ++rt)
      #pragma unroll
      for (int ct = 0; ct < 2; ++ct)
        #pragma unroll
        for (int r = 0; r < 4; ++r) m = fmaxf(m, acc[rt][ct][r]);
    #pragma unroll
    for (int off = 1; off < 64; off <<= 1) m = fmaxf(m, __shfl_xor(m, off));
    if (lane == 0) wmax[w] = m;
    __syncthreads();
    m = fmaxf(fmaxf(wmax[0], wmax[1]), fmaxf(wmax[2], wmax[3]));
    float inv = 1.0f / m;
    #pragma unroll
    for (int rt = 0; rt < 2; ++rt)
      #pragma unroll
      for (int ct = 0; ct < 2; ++ct) acc[rt][ct] *= inv;
    logscale += logf(m);

    int nxt = cur ^ 1;
    #pragma unroll
    for (int rt = 0; rt < 2; ++rt)
      #pragma unroll
      for (int ct = 0; ct < 2; ++ct)
        #pragma unroll
        for (int r = 0; r < 4; ++r) {
          int row = wi * 32 + rt * 16 + lg * 4 + r;
          int col = wj * 32 + ct * 16 + lr;
          L[nxt][(col * 64 + row) ^ ((col & 7) << 3)] = f2bf(acc[rt][ct][r]);
        }
    __syncthreads();
    cur = nxt;
  }

  float* Mo = G2T + (((size_t)b * 16 + g) << 12);
  #pragma unroll
  for (int rt = 0; rt < 2; ++rt)
    #pragma unroll
    for (int ct = 0; ct < 2; ++ct)
      #pragma unroll
      for (int r = 0; r < 4; ++r) {
        int row = wi * 32 + rt * 16 + lg * 4 + r;
        int col = wj * 32 + ct * 16 + lr;
        Mo[row * 64 + col] = acc[rt][ct][r];
      }

  if (w == 0 && lane == 0) auxg[b * 16 + g] = logscale;
}

// ---------------- K6: final combine (16 group matrices per batch) -----------
__global__ __launch_bounds__(64) void mmm_combine_kernel(
    const float* __restrict__ pi_logits, const float* __restrict__ ehat,
    const float* __restrict__ cmax, const float* __restrict__ G2T,
    const float* __restrict__ auxg, float* __restrict__ out) {
  int b = blockIdx.x, lane = threadIdx.x;
  __shared__ __align__(16) float alds[64];

  float pv = pi_logits[lane];
  float mx = pv;
  #pragma unroll
  for (int off = 1; off < 64; off <<= 1) mx = fmaxf(mx, __shfl_xor(mx, off));
  float pe = expf(pv - mx);
  float ps = pe;
  #pragma unroll
  for (int off = 1; off < 64; off <<= 1) ps += __shfl_xor(ps, off);

  float a = (pe / ps) * ehat[(size_t)b * 4096 * 64 + lane];
  double logtot = (double)cmax[(size_t)b * 4096];
  alds[lane] = a;
  __builtin_amdgcn_wave_barrier();

  for (int g = 0; g < 16; ++g) {
    const float* Mc = G2T + (((size_t)b * 16 + g) << 12) + lane * 64;
    f32x4 a4 = {0.f, 0.f, 0.f, 0.f};
    #pragma unroll
    for (int i = 0; i < 64; i += 4) {
      f32x4 mv = *(const f32x4*)&Mc[i];
      f32x4 av = *(const f32x4*)&alds[i];
      a4 += mv * av;
    }
    float acc = (a4[0] + a4[1]) + (a4[2] + a4[3]);
    float s = acc;
    #pragma unroll
    for (int off = 1; off < 64; off <<= 1) s += __shfl_xor(s, off);
    logtot += (double)(auxg[b * 16 + g] + logf(s));
    float an = acc / s;
    __builtin_amdgcn_wave_barrier();
    alds[lane] = an;
    __builtin_amdgcn_wave_barrier();
  }
  if (lane == 0) out[b] = (float)logtot;
}

extern "C" void kernel_launch(void* const* d_in, const int* in_sizes, int n_in,
                              void* d_out, int out_size, void* d_ws, size_t ws_size,
                              hipStream_t stream) {
  const float* X      = (const float*)d_in[0];
  const float* pi_l   = (const float*)d_in[1];
  const float* tr_l   = (const float*)d_in[2];
  const float* wl     = (const float*)d_in[3];
  const float* means  = (const float*)d_in[4];
  const float* lvs    = (const float*)d_in[5];
  float* out = (float*)d_out;

  float* ws = (float*)d_ws;
  short* Gt      = (short*)ws;                 // 131072 shorts = 65536 f32
  float* const_c = ws + 65536;                 // 512
  short* WTbf    = (short*)(ws + 66048);       // 4096 shorts = 2048 f32
  float* cmaxp   = ws + 68608;                 // 32768
  float* ehat    = ws + 101376;                // 2097152
  short* XeP     = (short*)(ws + 2198528);     // 16 MB
  float* NT      = ws + 2198528;               // aliases XeP (dead after emis); 8388608 f32
  float* aux     = ws + 10587136;              // 4096 (256 chunks x 2 strips x 8 b)
  float* G2T     = ws + 10591232;              // 524288 (8 b x 16 g x 4096)
  float* auxg    = ws + 11115520;              // 128

  mmm_w_kernel<<<64, 64, 0, stream>>>(tr_l, WTbf);
  mmm_prep_kernel<<<512, 128, 0, stream>>>(means, lvs, wl, Gt, const_c);
  mmm_prepxe_kernel<<<512, 256, 0, stream>>>(X, XeP);
  mmm_emis_kernel<<<256, 512, 0, stream>>>(Gt, XeP, const_c, ehat, cmaxp);
  mmm_chunk_kernel<<<dim3(256, 8), 128, 0, stream>>>(WTbf, ehat, cmaxp, NT, aux);
  mmm_merge_kernel<<<dim3(16, 8), 256, 0, stream>>>(NT, aux, G2T, auxg);
  mmm_combine_kernel<<<8, 64, 0, stream>>>(pi_l, ehat, cmaxp, G2T, auxg, out);
}

// Round 3
// 133.939 us; speedup vs baseline: 1.0358x; 1.0358x over previous
//
#include <hip/hip_runtime.h>
#include <hip/hip_bf16.h>
#include <math.h>

#define LOG2PI_F 1.8378770664093453f

typedef __attribute__((ext_vector_type(8))) short bf16x8;
typedef __attribute__((ext_vector_type(4))) float f32x4;
typedef __attribute__((ext_vector_type(16))) float f32x16;

static __device__ inline short f2bf(float x) {
  __hip_bfloat16 h = __float2bfloat16(x);
  return *reinterpret_cast<short*>(&h);
}
static __device__ inline unsigned pack2(float lo, float hi) {
  unsigned a = (unsigned)(unsigned short)f2bf(lo);
  unsigned b = (unsigned)(unsigned short)f2bf(hi);
  return a | (b << 16);
}
static __device__ inline f32x4 mfma16(bf16x8 a, bf16x8 b, f32x4 c) {
  return __builtin_amdgcn_mfma_f32_16x16x32_bf16(a, b, c, 0, 0, 0);
}
static __device__ inline f32x16 mfma32(bf16x8 a, bf16x8 b, f32x16 c) {
  return __builtin_amdgcn_mfma_f32_32x32x16_bf16(a, b, c, 0, 0, 0);
}

// ---------------- K0: WTbf[k'][k] = bf16(softmax_row_k(tl)[k']) -------------
__global__ __launch_bounds__(64) void mmm_w_kernel(
    const float* __restrict__ tl, short* __restrict__ WTbf) {
  int r = blockIdx.x, lane = threadIdx.x;
  float v = tl[r * 64 + lane];
  float mx = v;
  #pragma unroll
  for (int off = 1; off < 64; off <<= 1) mx = fmaxf(mx, __shfl_xor(mx, off));
  float e = expf(v - mx);
  float s = e;
  #pragma unroll
  for (int off = 1; off < 64; off <<= 1) s += __shfl_xor(s, off);
  WTbf[lane * 64 + r] = f2bf(e / s);
}

// ---------------- K1: prep Gt bf16 [512][256] + const_c[512] ----------------
__global__ __launch_bounds__(128) void mmm_prep_kernel(
    const float* __restrict__ means, const float* __restrict__ log_vars,
    const float* __restrict__ weight_logits,
    short* __restrict__ Gt, float* __restrict__ const_c) {
  int sm = blockIdx.x;
  int s = sm >> 3, m = sm & 7;
  int d = threadIdx.x;
  float lv = log_vars[sm * 128 + d];
  float iv = expf(-lv);
  float mu = means[sm * 128 + d];
  float miv = mu * iv;
  Gt[sm * 256 + d] = f2bf(miv);
  Gt[sm * 256 + 128 + d] = f2bf(-0.5f * iv);
  float v = mu * miv + lv;
  #pragma unroll
  for (int off = 1; off < 64; off <<= 1) v += __shfl_xor(v, off);
  __shared__ float red[2];
  if ((d & 63) == 0) red[d >> 6] = v;
  __syncthreads();
  if (d == 0) {
    float tot = red[0] + red[1];
    float wl[8];
    float mx = -3.4e38f;
    #pragma unroll
    for (int j = 0; j < 8; ++j) { wl[j] = weight_logits[s * 8 + j]; mx = fmaxf(mx, wl[j]); }
    float sum = 0.f;
    #pragma unroll
    for (int j = 0; j < 8; ++j) sum += expf(wl[j] - mx);
    float lmw = wl[m] - mx - logf(sum);
    const_c[sm] = -0.5f * (tot + 128.0f * LOG2PI_F) + lmw;
  }
}

// ---------------- K2: prep XeP bf16 packed [8 kb2][32768 bt][32 kk] ----------
__global__ __launch_bounds__(256) void mmm_prepxe_kernel(
    const float* __restrict__ X, short* __restrict__ XeP) {
  int q = blockIdx.x >> 7;
  int bt = ((blockIdx.x & 127) << 8) + threadIdx.x;
  const float4* src = (const float4*)(X + (size_t)bt * 128 + q * 32);
  float xv[32];
  #pragma unroll
  for (int i = 0; i < 8; ++i) {
    float4 v = src[i];
    xv[4 * i] = v.x; xv[4 * i + 1] = v.y; xv[4 * i + 2] = v.z; xv[4 * i + 3] = v.w;
  }
  size_t base1 = ((size_t)q * 32768 + bt) * 32;
  size_t base2 = ((size_t)(q + 4) * 32768 + bt) * 32;
  int bx = bt & 3;
  #pragma unroll
  for (int g = 0; g < 4; ++g) {
    bf16x8 t1, t2;
    #pragma unroll
    for (int j = 0; j < 8; ++j) {
      float x = xv[g * 8 + j];
      t1[j] = f2bf(x);
      t2[j] = f2bf(x * x);
    }
    int gs = (g ^ bx) * 8;
    *(bf16x8*)&XeP[base1 + gs] = t1;
    *(bf16x8*)&XeP[base2 + gs] = t2;
  }
}

// ---------------- K3: MFMA emission GEMM, C[sm=512][bt=64-tile] ------------
__global__ __launch_bounds__(512) void mmm_emis_kernel(
    const short* __restrict__ Gt, const short* __restrict__ XeP,
    const float* __restrict__ const_c,
    float* __restrict__ ehat, float* __restrict__ cmax) {
  __shared__ __align__(16) short Bt[16384];  // 32 KB
  __shared__ __align__(16) float ccs[512];
  __shared__ float wavemax[8][64];
  __shared__ float colmax[64];
  int tid = threadIdx.x;
  int w = tid >> 6, lane = tid & 63, lr = lane & 15, lg = lane >> 4;

  ccs[tid] = const_c[tid];

  bf16x8 gf[4][8];
  #pragma unroll
  for (int rt = 0; rt < 4; ++rt) {
    int row = w * 64 + rt * 16 + lr;
    #pragma unroll
    for (int kc = 0; kc < 8; ++kc)
      gf[rt][kc] = *(const bf16x8*)&Gt[row * 256 + kc * 32 + lg * 8];
  }

  uint4 sreg[4];
  {
    size_t bt0 = (size_t)blockIdx.x * 64;
    #pragma unroll
    for (int r = 0; r < 4; ++r) {
      int ofs = r * 8192 + tid * 16;
      int kb2 = ofs >> 12, rem = ofs & 4095;
      sreg[r] = *(const uint4*)((const char*)XeP + ((size_t)kb2 * 32768 + bt0) * 64 + rem);
    }
  }

  for (int it = 0; it < 2; ++it) {
    int bt0 = (blockIdx.x + it * 256) * 64;
    __syncthreads();
    #pragma unroll
    for (int r = 0; r < 4; ++r)
      *(uint4*)((char*)Bt + r * 8192 + tid * 16) = sreg[r];
    __syncthreads();
    if (it == 0) {
      size_t bt0n = ((size_t)blockIdx.x + 256) * 64;
      #pragma unroll
      for (int r = 0; r < 4; ++r) {
        int ofs = r * 8192 + tid * 16;
        int kb2 = ofs >> 12, rem = ofs & 4095;
        sreg[r] = *(const uint4*)((const char*)XeP + ((size_t)kb2 * 32768 + bt0n) * 64 + rem);
      }
    }

    f32x4 acc[4][4];
    #pragma unroll
    for (int rt = 0; rt < 4; ++rt)
      #pragma unroll
      for (int ct = 0; ct < 4; ++ct)
        acc[rt][ct] = (f32x4){0.f, 0.f, 0.f, 0.f};

    #pragma unroll
    for (int kc = 0; kc < 8; ++kc) {
      bf16x8 bfr[4];
      #pragma unroll
      for (int ct = 0; ct < 4; ++ct) {
        int btL = ct * 16 + lr;
        bfr[ct] = *(const bf16x8*)&Bt[kc * 2048 + btL * 32 + ((lg ^ (btL & 3)) * 8)];
      }
      #pragma unroll
      for (int rt = 0; rt < 4; ++rt)
        #pragma unroll
        for (int ct = 0; ct < 4; ++ct)
          acc[rt][ct] = mfma16(gf[rt][kc], bfr[ct], acc[rt][ct]);
    }

    float lse[4][4];
    #pragma unroll
    for (int rt = 0; rt < 4; ++rt) {
      f32x4 cc = *(f32x4*)&ccs[w * 64 + rt * 16 + lg * 4];
      #pragma unroll
      for (int ct = 0; ct < 4; ++ct) {
        f32x4 v = acc[rt][ct] + cc;
        float mx = fmaxf(fmaxf(v[0], v[1]), fmaxf(v[2], v[3]));
        mx = fmaxf(mx, __shfl_xor(mx, 16));
        float sum = expf(v[0] - mx) + expf(v[1] - mx) + expf(v[2] - mx) + expf(v[3] - mx);
        sum += __shfl_xor(sum, 16);
        lse[rt][ct] = mx + logf(sum);
      }
    }
    #pragma unroll
    for (int ct = 0; ct < 4; ++ct) {
      float cm = fmaxf(fmaxf(lse[0][ct], lse[1][ct]), fmaxf(lse[2][ct], lse[3][ct]));
      cm = fmaxf(cm, __shfl_xor(cm, 32));
      if (lg == 0) wavemax[w][ct * 16 + lr] = cm;
    }
    __syncthreads();
    if (w == 0) {
      float cm = wavemax[0][lane];
      #pragma unroll
      for (int ww = 1; ww < 8; ++ww) cm = fmaxf(cm, wavemax[ww][lane]);
      colmax[lane] = cm;
      cmax[(size_t)bt0 + lane] = cm;
    }
    __syncthreads();
    #pragma unroll
    for (int ct = 0; ct < 4; ++ct) {
      float cm = colmax[ct * 16 + lr];
      #pragma unroll
      for (int rt = 0; rt < 4; ++rt) {
        float v = expf(lse[rt][ct] - cm);
        if (!(lg & 1))
          ehat[((size_t)bt0 + ct * 16 + lr) * 64 + (w * 8 + rt * 2 + (lg >> 1))] = v;
      }
    }
  }
}

// ---------------- K4: per-chunk product, single fat wave ---------------------
// REDESIGN (r3): one 64-lane wave carries the FULL 64-col state as packed
// bf16 (P only; no f32 carried state). Rationale: K4 time was invariant at
// ~43us under 2x parallelism / 0.5x depth => wave-steps/SIMD (64) was the
// invariant, per-step cost latency-dominated with ~2 effective waves/SIMD.
// One fat wave: wave-steps/SIMD 64->32, in-wave ILP-2 between the two
// 32-col strips, shared e-loads, shared per-chunk rescale (aux scalar).
__global__ __launch_bounds__(64) void mmm_chunk_kernel(
    const short* __restrict__ WTbf, const float* __restrict__ ehat,
    const float* __restrict__ cmax, float* __restrict__ NT,
    float* __restrict__ aux) {
  int chunk = blockIdx.x, b = blockIdx.y;
  int lane = threadIdx.x;
  int l31 = lane & 31, hi = lane >> 5;

  // A = W^T: af[wi][kb], row = wi*32+l31, k = kb*16 + hi*8 + j (shared by strips)
  bf16x8 af[2][4];
  #pragma unroll
  for (int wi = 0; wi < 2; ++wi)
    #pragma unroll
    for (int kb = 0; kb < 4; ++kb)
      af[wi][kb] = *(const bf16x8*)&WTbf[(wi * 32 + l31) * 64 + kb * 16 + hi * 8];

  // packed state: P[s][cm][q][p] = bf16 rows {32cm+8q+4hi+2p, +1} at col s*32+l31
  unsigned P[2][2][4][2];
  #pragma unroll
  for (int s = 0; s < 2; ++s) {
    int col = s * 32 + l31;
    #pragma unroll
    for (int cm = 0; cm < 2; ++cm)
      #pragma unroll
      for (int q = 0; q < 4; ++q)
        #pragma unroll
        for (int p = 0; p < 2; ++p) {
          int row = 32 * cm + 8 * q + 4 * hi + 2 * p;
          unsigned lo = (row == col) ? 0x3F80u : 0u;       // bf16(1.0)
          unsigned h16 = (row + 1 == col) ? 0x3F80u : 0u;
          P[s][cm][q][p] = lo | (h16 << 16);
        }
  }

  int t0 = (chunk == 0) ? 1 : chunk * 16;
  int nsteps = (chunk == 0) ? 15 : 16;
  const float* eb = ehat + (size_t)b * 4096 * 64;

  float logscale = 0.f;

  for (int it = 0; it < nsteps; ++it) {
    // e for this step, rows cm*32+q*8+hi*4..+3 — shared by both strips
    f32x4 ev[2][4];
    #pragma unroll
    for (int cm = 0; cm < 2; ++cm)
      #pragma unroll
      for (int q = 0; q < 4; ++q)
        ev[cm][q] = *(const f32x4*)&eb[(size_t)(t0 + it) * 64 + cm * 32 + q * 8 + hi * 4];

    #pragma unroll
    for (int s = 0; s < 2; ++s) {
      // B[kb]: k = kb*16 + 8*hi + j; one permlane32_swap per (quad-pair, p)
      bf16x8 B[4];
      #pragma unroll
      for (int kb = 0; kb < 4; ++kb) {
        int cm = kb >> 1, kbl = kb & 1;
        int4 wrd;
        #pragma unroll
        for (int p = 0; p < 2; ++p) {
          unsigned avv = P[s][cm][2 * kbl + 1][p];
          unsigned bvv = P[s][cm][2 * kbl][p];
          asm("v_permlane32_swap_b32 %0, %1" : "+v"(avv), "+v"(bvv));
          if (p == 0) { wrd.x = (int)bvv; wrd.z = (int)avv; }
          else        { wrd.y = (int)bvv; wrd.w = (int)avv; }
        }
        B[kb] = *(bf16x8*)&wrd;
      }

      f32x16 d0, d1;
      #pragma unroll
      for (int r = 0; r < 16; ++r) { d0[r] = 0.f; d1[r] = 0.f; }
      #pragma unroll
      for (int kb = 0; kb < 4; ++kb) {
        d0 = mfma32(af[0][kb], B[kb], d0);
        d1 = mfma32(af[1][kb], B[kb], d1);
      }

      // P = pack(d * e): reg 4q+s_ -> row 32cm+8q+4hi+s_
      #pragma unroll
      for (int q = 0; q < 4; ++q)
        #pragma unroll
        for (int p = 0; p < 2; ++p) {
          P[s][0][q][p] = pack2(d0[4 * q + 2 * p] * ev[0][q][2 * p],
                                d0[4 * q + 2 * p + 1] * ev[0][q][2 * p + 1]);
          P[s][1][q][p] = pack2(d1[4 * q + 2 * p] * ev[1][q][2 * p],
                                d1[4 * q + 2 * p + 1] * ev[1][q][2 * p + 1]);
        }
    }

    if ((it & 7) == 7) {  // whole-chunk rescale, applied in place on P
      float m = 0.f;
      #pragma unroll
      for (int s = 0; s < 2; ++s)
        #pragma unroll
        for (int cm = 0; cm < 2; ++cm)
          #pragma unroll
          for (int q = 0; q < 4; ++q)
            #pragma unroll
            for (int p = 0; p < 2; ++p) {
              unsigned u = P[s][cm][q][p];
              m = fmaxf(m, __uint_as_float(u << 16));
              m = fmaxf(m, __uint_as_float(u & 0xffff0000u));
            }
      #pragma unroll
      for (int off = 1; off < 64; off <<= 1) m = fmaxf(m, __shfl_xor(m, off));
      float inv = 1.0f / m;
      #pragma unroll
      for (int s = 0; s < 2; ++s)
        #pragma unroll
        for (int cm = 0; cm < 2; ++cm)
          #pragma unroll
          for (int q = 0; q < 4; ++q)
            #pragma unroll
            for (int p = 0; p < 2; ++p) {
              unsigned u = P[s][cm][q][p];
              P[s][cm][q][p] = pack2(__uint_as_float(u << 16) * inv,
                                     __uint_as_float(u & 0xffff0000u) * inv);
            }
      logscale += logf(m);
    }
  }

  // store N_c f32 row-major [row][col] (unpack bf16 state; K5 rounds to bf16
  // anyway, so values are identical to the old f32-carried path)
  float* No = NT + (((size_t)b * 256 + chunk) << 12);
  #pragma unroll
  for (int s = 0; s < 2; ++s)
    #pragma unroll
    for (int cm = 0; cm < 2; ++cm)
      #pragma unroll
      for (int q = 0; q < 4; ++q)
        #pragma unroll
        for (int p = 0; p < 2; ++p) {
          int row = 32 * cm + 8 * q + 4 * hi + 2 * p;
          int col = s * 32 + l31;
          unsigned u = P[s][cm][q][p];
          No[row * 64 + col] = __uint_as_float(u << 16);
          No[(row + 1) * 64 + col] = __uint_as_float(u & 0xffff0000u);
        }

  // aux[b][chunk] = sum cmax + chunk logscale (single scale, whole chunk)
  float cs = (lane < nsteps) ? cmax[(size_t)b * 4096 + t0 + lane] : 0.f;
  #pragma unroll
  for (int off = 1; off < 64; off <<= 1) cs += __shfl_xor(cs, off);
  if (lane == 0) aux[(size_t)b * 256 + chunk] = cs + logscale;
}

// ---------------- K5: merge 16 chunks -> group matrix (16 groups/batch) -----
// Q' = N_cc * Q; N_cc now uniformly scaled (single aux scalar per chunk).
__global__ __launch_bounds__(256) void mmm_merge_kernel(
    const float* __restrict__ NT, const float* __restrict__ aux,
    float* __restrict__ G2T, float* __restrict__ auxg) {
  int g = blockIdx.x, b = blockIdx.y;
  int tid = threadIdx.x;
  int w = tid >> 6, lane = tid & 63;
  int wi = w >> 1, wj = w & 1;
  int lr = lane & 15, lg = lane >> 4;

  __shared__ __align__(16) short L[2][4096];
  __shared__ float wmax[4];

  for (int idx = tid; idx < 4096; idx += 256) {
    int j = idx >> 6, k = idx & 63;
    L[0][idx ^ ((j & 7) << 3)] = (j == k) ? (short)0x3F80 : (short)0;
  }
  __syncthreads();

  int cbase = b * 256 + g * 16;

  float logscale = 0.f;
  int cur = 0;
  f32x4 acc[2][2];

  f32x4 apre[2][2][2];
  {
    const float* Mc = NT + ((size_t)cbase << 12);
    #pragma unroll
    for (int rt = 0; rt < 2; ++rt)
      #pragma unroll
      for (int kc = 0; kc < 2; ++kc) {
        const float* src = Mc + (wi * 32 + rt * 16 + lr) * 64 + kc * 32 + lg * 8;
        apre[rt][kc][0] = *(const f32x4*)src;
        apre[rt][kc][1] = *(const f32x4*)(src + 4);
      }
  }

  for (int cc = 0; cc < 16; ++cc) {
    f32x4 acur[2][2][2];
    #pragma unroll
    for (int rt = 0; rt < 2; ++rt)
      #pragma unroll
      for (int kc = 0; kc < 2; ++kc) {
        acur[rt][kc][0] = apre[rt][kc][0];
        acur[rt][kc][1] = apre[rt][kc][1];
      }
    if (cc < 15) {
      const float* Mc = NT + ((size_t)(cbase + cc + 1) << 12);
      #pragma unroll
      for (int rt = 0; rt < 2; ++rt)
        #pragma unroll
        for (int kc = 0; kc < 2; ++kc) {
          const float* src = Mc + (wi * 32 + rt * 16 + lr) * 64 + kc * 32 + lg * 8;
          apre[rt][kc][0] = *(const f32x4*)src;
          apre[rt][kc][1] = *(const f32x4*)(src + 4);
        }
    }

    // single scale per chunk: just accumulate the log
    logscale += aux[cbase + cc];

    bf16x8 afr[2][2];
    #pragma unroll
    for (int rt = 0; rt < 2; ++rt)
      #pragma unroll
      for (int kc = 0; kc < 2; ++kc) {
        bf16x8 f;
        #pragma unroll
        for (int u = 0; u < 4; ++u) {
          f[u] = f2bf(acur[rt][kc][0][u]);
          f[4 + u] = f2bf(acur[rt][kc][1][u]);
        }
        afr[rt][kc] = f;
      }

    bf16x8 bfr[2][2];
    #pragma unroll
    for (int ct = 0; ct < 2; ++ct) {
      int j = wj * 32 + ct * 16 + lr;
      int sw = (j & 7) << 3;
      #pragma unroll
      for (int kc = 0; kc < 2; ++kc)
        bfr[ct][kc] = *(const bf16x8*)&L[cur][(j * 64 + kc * 32 + lg * 8) ^ sw];
    }

    #pragma unroll
    for (int rt = 0; rt < 2; ++rt)
      #pragma unroll
      for (int ct = 0; ct < 2; ++ct) {
        f32x4 c = {0.f, 0.f, 0.f, 0.f};
        c = mfma16(afr[rt][0], bfr[ct][0], c);
        c = mfma16(afr[rt][1], bfr[ct][1], c);
        acc[rt][ct] = c;
      }

    float m = 0.f;
    #pragma unroll
    for (int rt = 0; rt < 2; ++rt)
      #pragma unroll
      for (int ct = 0; ct < 2; ++ct)
        #pragma unroll
        for (int r = 0; r < 4; ++r) m = fmaxf(m, acc[rt][ct][r]);
    #pragma unroll
    for (int off = 1; off < 64; off <<= 1) m = fmaxf(m, __shfl_xor(m, off));
    if (lane == 0) wmax[w] = m;
    __syncthreads();
    m = fmaxf(fmaxf(wmax[0], wmax[1]), fmaxf(wmax[2], wmax[3]));
    float inv = 1.0f / m;
    #pragma unroll
    for (int rt = 0; rt < 2; ++rt)
      #pragma unroll
      for (int ct = 0; ct < 2; ++ct) acc[rt][ct] *= inv;
    logscale += logf(m);

    int nxt = cur ^ 1;
    #pragma unroll
    for (int rt = 0; rt < 2; ++rt)
      #pragma unroll
      for (int ct = 0; ct < 2; ++ct)
        #pragma unroll
        for (int r = 0; r < 4; ++r) {
          int row = wi * 32 + rt * 16 + lg * 4 + r;
          int col = wj * 32 + ct * 16 + lr;
          L[nxt][(col * 64 + row) ^ ((col & 7) << 3)] = f2bf(acc[rt][ct][r]);
        }
    __syncthreads();
    cur = nxt;
  }

  float* Mo = G2T + (((size_t)b * 16 + g) << 12);
  #pragma unroll
  for (int rt = 0; rt < 2; ++rt)
    #pragma unroll
    for (int ct = 0; ct < 2; ++ct)
      #pragma unroll
      for (int r = 0; r < 4; ++r) {
        int row = wi * 32 + rt * 16 + lg * 4 + r;
        int col = wj * 32 + ct * 16 + lr;
        Mo[row * 64 + col] = acc[rt][ct][r];
      }

  if (w == 0 && lane == 0) auxg[b * 16 + g] = logscale;
}

// ---------------- K6: final combine (16 group matrices per batch) -----------
__global__ __launch_bounds__(64) void mmm_combine_kernel(
    const float* __restrict__ pi_logits, const float* __restrict__ ehat,
    const float* __restrict__ cmax, const float* __restrict__ G2T,
    const float* __restrict__ auxg, float* __restrict__ out) {
  int b = blockIdx.x, lane = threadIdx.x;
  __shared__ __align__(16) float alds[64];

  float pv = pi_logits[lane];
  float mx = pv;
  #pragma unroll
  for (int off = 1; off < 64; off <<= 1) mx = fmaxf(mx, __shfl_xor(mx, off));
  float pe = expf(pv - mx);
  float ps = pe;
  #pragma unroll
  for (int off = 1; off < 64; off <<= 1) ps += __shfl_xor(ps, off);

  float a = (pe / ps) * ehat[(size_t)b * 4096 * 64 + lane];
  double logtot = (double)cmax[(size_t)b * 4096];
  alds[lane] = a;
  __builtin_amdgcn_wave_barrier();

  for (int g = 0; g < 16; ++g) {
    const float* Mc = G2T + (((size_t)b * 16 + g) << 12) + lane * 64;
    f32x4 a4 = {0.f, 0.f, 0.f, 0.f};
    #pragma unroll
    for (int i = 0; i < 64; i += 4) {
      f32x4 mv = *(const f32x4*)&Mc[i];
      f32x4 av = *(const f32x4*)&alds[i];
      a4 += mv * av;
    }
    float acc = (a4[0] + a4[1]) + (a4[2] + a4[3]);
    float s = acc;
    #pragma unroll
    for (int off = 1; off < 64; off <<= 1) s += __shfl_xor(s, off);
    logtot += (double)(auxg[b * 16 + g] + logf(s));
    float an = acc / s;
    __builtin_amdgcn_wave_barrier();
    alds[lane] = an;
    __builtin_amdgcn_wave_barrier();
  }
  if (lane == 0) out[b] = (float)logtot;
}

extern "C" void kernel_launch(void* const* d_in, const int* in_sizes, int n_in,
                              void* d_out, int out_size, void* d_ws, size_t ws_size,
                              hipStream_t stream) {
  const float* X      = (const float*)d_in[0];
  const float* pi_l   = (const float*)d_in[1];
  const float* tr_l   = (const float*)d_in[2];
  const float* wl     = (const float*)d_in[3];
  const float* means  = (const float*)d_in[4];
  const float* lvs    = (const float*)d_in[5];
  float* out = (float*)d_out;

  float* ws = (float*)d_ws;
  short* Gt      = (short*)ws;                 // 131072 shorts = 65536 f32
  float* const_c = ws + 65536;                 // 512
  short* WTbf    = (short*)(ws + 66048);       // 4096 shorts = 2048 f32
  float* cmaxp   = ws + 68608;                 // 32768
  float* ehat    = ws + 101376;                // 2097152
  short* XeP     = (short*)(ws + 2198528);     // 16 MB
  float* NT      = ws + 2198528;               // aliases XeP (dead after emis); 8388608 f32
  float* aux     = ws + 10587136;              // 2048 (256 chunks x 8 b)
  float* G2T     = ws + 10591232;              // 524288 (8 b x 16 g x 4096)
  float* auxg    = ws + 11115520;              // 128

  mmm_w_kernel<<<64, 64, 0, stream>>>(tr_l, WTbf);
  mmm_prep_kernel<<<512, 128, 0, stream>>>(means, lvs, wl, Gt, const_c);
  mmm_prepxe_kernel<<<512, 256, 0, stream>>>(X, XeP);
  mmm_emis_kernel<<<256, 512, 0, stream>>>(Gt, XeP, const_c, ehat, cmaxp);
  mmm_chunk_kernel<<<dim3(256, 8), 64, 0, stream>>>(WTbf, ehat, cmaxp, NT, aux);
  mmm_merge_kernel<<<dim3(16, 8), 256, 0, stream>>>(NT, aux, G2T, auxg);
  mmm_combine_kernel<<<8, 64, 0, stream>>>(pi_l, ehat, cmaxp, G2T, auxg, out);
}

// Round 4
// 128.099 us; speedup vs baseline: 1.0830x; 1.0456x over previous
//
#include <hip/hip_runtime.h>
#include <hip/hip_bf16.h>
#include <math.h>

#define LOG2PI_F 1.8378770664093453f

typedef __attribute__((ext_vector_type(8))) short bf16x8;
typedef __attribute__((ext_vector_type(4))) float f32x4;
typedef __attribute__((ext_vector_type(16))) float f32x16;

static __device__ inline short f2bf(float x) {
  __hip_bfloat16 h = __float2bfloat16(x);
  return *reinterpret_cast<short*>(&h);
}
// HW packed f32->bf16 (RNE). Within-session A/B (r1 vs r2: 137.6 vs 138.7)
// shows this is >= the software pack here, contra m240's probe: K4/K2/K5 are
// pack-dense (32 packs/step in K4), so the ~5x static VALU saving wins.
static __device__ inline unsigned cvtpk(float lo, float hi) {
  unsigned r;
  asm("v_cvt_pk_bf16_f32 %0, %1, %2" : "=v"(r) : "v"(lo), "v"(hi));
  return r;
}
static __device__ inline f32x4 mfma16(bf16x8 a, bf16x8 b, f32x4 c) {
  return __builtin_amdgcn_mfma_f32_16x16x32_bf16(a, b, c, 0, 0, 0);
}
static __device__ inline f32x16 mfma32(bf16x8 a, bf16x8 b, f32x16 c) {
  return __builtin_amdgcn_mfma_f32_32x32x16_bf16(a, b, c, 0, 0, 0);
}

// ---------------- K0: WTbf[k'][k] = bf16(softmax_row_k(tl)[k']) -------------
__global__ __launch_bounds__(64) void mmm_w_kernel(
    const float* __restrict__ tl, short* __restrict__ WTbf) {
  int r = blockIdx.x, lane = threadIdx.x;
  float v = tl[r * 64 + lane];
  float mx = v;
  #pragma unroll
  for (int off = 1; off < 64; off <<= 1) mx = fmaxf(mx, __shfl_xor(mx, off));
  float e = expf(v - mx);
  float s = e;
  #pragma unroll
  for (int off = 1; off < 64; off <<= 1) s += __shfl_xor(s, off);
  WTbf[lane * 64 + r] = f2bf(e / s);
}

// ---------------- K1: prep Gt bf16 [512][256] + const_c[512] ----------------
__global__ __launch_bounds__(128) void mmm_prep_kernel(
    const float* __restrict__ means, const float* __restrict__ log_vars,
    const float* __restrict__ weight_logits,
    short* __restrict__ Gt, float* __restrict__ const_c) {
  int sm = blockIdx.x;
  int s = sm >> 3, m = sm & 7;
  int d = threadIdx.x;
  float lv = log_vars[sm * 128 + d];
  float iv = expf(-lv);
  float mu = means[sm * 128 + d];
  float miv = mu * iv;
  Gt[sm * 256 + d] = f2bf(miv);
  Gt[sm * 256 + 128 + d] = f2bf(-0.5f * iv);
  float v = mu * miv + lv;
  #pragma unroll
  for (int off = 1; off < 64; off <<= 1) v += __shfl_xor(v, off);
  __shared__ float red[2];
  if ((d & 63) == 0) red[d >> 6] = v;
  __syncthreads();
  if (d == 0) {
    float tot = red[0] + red[1];
    float wl[8];
    float mx = -3.4e38f;
    #pragma unroll
    for (int j = 0; j < 8; ++j) { wl[j] = weight_logits[s * 8 + j]; mx = fmaxf(mx, wl[j]); }
    float sum = 0.f;
    #pragma unroll
    for (int j = 0; j < 8; ++j) sum += expf(wl[j] - mx);
    float lmw = wl[m] - mx - logf(sum);
    const_c[sm] = -0.5f * (tot + 128.0f * LOG2PI_F) + lmw;
  }
}

// ---------------- K2: prep XeP bf16 packed [8 kb2][32768 bt][32 kk] ----------
__global__ __launch_bounds__(256) void mmm_prepxe_kernel(
    const float* __restrict__ X, short* __restrict__ XeP) {
  int q = blockIdx.x >> 7;
  int bt = ((blockIdx.x & 127) << 8) + threadIdx.x;
  const float4* src = (const float4*)(X + (size_t)bt * 128 + q * 32);
  float xv[32];
  #pragma unroll
  for (int i = 0; i < 8; ++i) {
    float4 v = src[i];
    xv[4 * i] = v.x; xv[4 * i + 1] = v.y; xv[4 * i + 2] = v.z; xv[4 * i + 3] = v.w;
  }
  size_t base1 = ((size_t)q * 32768 + bt) * 32;
  size_t base2 = ((size_t)(q + 4) * 32768 + bt) * 32;
  int bx = bt & 3;
  #pragma unroll
  for (int g = 0; g < 4; ++g) {
    unsigned w1[4], w2[4];
    #pragma unroll
    for (int j = 0; j < 4; ++j) {
      float a = xv[g * 8 + 2 * j], c = xv[g * 8 + 2 * j + 1];
      w1[j] = cvtpk(a, c);
      w2[j] = cvtpk(a * a, c * c);
    }
    int gs = (g ^ bx) * 8;
    *(uint4*)&XeP[base1 + gs] = *(uint4*)w1;
    *(uint4*)&XeP[base2 + gs] = *(uint4*)w2;
  }
}

// ---------------- K3: MFMA emission GEMM, C[sm=512][bt=64-tile] ------------
__global__ __launch_bounds__(512) void mmm_emis_kernel(
    const short* __restrict__ Gt, const short* __restrict__ XeP,
    const float* __restrict__ const_c,
    float* __restrict__ ehat, float* __restrict__ cmax) {
  __shared__ __align__(16) short Bt[16384];  // 32 KB
  __shared__ __align__(16) float ccs[512];
  __shared__ float wavemax[8][64];
  __shared__ float colmax[64];
  int tid = threadIdx.x;
  int w = tid >> 6, lane = tid & 63, lr = lane & 15, lg = lane >> 4;

  ccs[tid] = const_c[tid];

  bf16x8 gf[4][8];
  #pragma unroll
  for (int rt = 0; rt < 4; ++rt) {
    int row = w * 64 + rt * 16 + lr;
    #pragma unroll
    for (int kc = 0; kc < 8; ++kc)
      gf[rt][kc] = *(const bf16x8*)&Gt[row * 256 + kc * 32 + lg * 8];
  }

  uint4 sreg[4];
  {
    size_t bt0 = (size_t)blockIdx.x * 64;
    #pragma unroll
    for (int r = 0; r < 4; ++r) {
      int ofs = r * 8192 + tid * 16;
      int kb2 = ofs >> 12, rem = ofs & 4095;
      sreg[r] = *(const uint4*)((const char*)XeP + ((size_t)kb2 * 32768 + bt0) * 64 + rem);
    }
  }

  for (int it = 0; it < 2; ++it) {
    int bt0 = (blockIdx.x + it * 256) * 64;
    __syncthreads();
    #pragma unroll
    for (int r = 0; r < 4; ++r)
      *(uint4*)((char*)Bt + r * 8192 + tid * 16) = sreg[r];
    __syncthreads();
    if (it == 0) {
      size_t bt0n = ((size_t)blockIdx.x + 256) * 64;
      #pragma unroll
      for (int r = 0; r < 4; ++r) {
        int ofs = r * 8192 + tid * 16;
        int kb2 = ofs >> 12, rem = ofs & 4095;
        sreg[r] = *(const uint4*)((const char*)XeP + ((size_t)kb2 * 32768 + bt0n) * 64 + rem);
      }
    }

    f32x4 acc[4][4];
    #pragma unroll
    for (int rt = 0; rt < 4; ++rt)
      #pragma unroll
      for (int ct = 0; ct < 4; ++ct)
        acc[rt][ct] = (f32x4){0.f, 0.f, 0.f, 0.f};

    #pragma unroll
    for (int kc = 0; kc < 8; ++kc) {
      bf16x8 bfr[4];
      #pragma unroll
      for (int ct = 0; ct < 4; ++ct) {
        int btL = ct * 16 + lr;
        bfr[ct] = *(const bf16x8*)&Bt[kc * 2048 + btL * 32 + ((lg ^ (btL & 3)) * 8)];
      }
      #pragma unroll
      for (int rt = 0; rt < 4; ++rt)
        #pragma unroll
        for (int ct = 0; ct < 4; ++ct)
          acc[rt][ct] = mfma16(gf[rt][kc], bfr[ct], acc[rt][ct]);
    }

    float lse[4][4];
    #pragma unroll
    for (int rt = 0; rt < 4; ++rt) {
      f32x4 cc = *(f32x4*)&ccs[w * 64 + rt * 16 + lg * 4];
      #pragma unroll
      for (int ct = 0; ct < 4; ++ct) {
        f32x4 v = acc[rt][ct] + cc;
        float mx = fmaxf(fmaxf(v[0], v[1]), fmaxf(v[2], v[3]));
        mx = fmaxf(mx, __shfl_xor(mx, 16));
        float sum = expf(v[0] - mx) + expf(v[1] - mx) + expf(v[2] - mx) + expf(v[3] - mx);
        sum += __shfl_xor(sum, 16);
        lse[rt][ct] = mx + logf(sum);
      }
    }
    #pragma unroll
    for (int ct = 0; ct < 4; ++ct) {
      float cm = fmaxf(fmaxf(lse[0][ct], lse[1][ct]), fmaxf(lse[2][ct], lse[3][ct]));
      cm = fmaxf(cm, __shfl_xor(cm, 32));
      if (lg == 0) wavemax[w][ct * 16 + lr] = cm;
    }
    __syncthreads();
    if (w == 0) {
      float cm = wavemax[0][lane];
      #pragma unroll
      for (int ww = 1; ww < 8; ++ww) cm = fmaxf(cm, wavemax[ww][lane]);
      colmax[lane] = cm;
      cmax[(size_t)bt0 + lane] = cm;
    }
    __syncthreads();
    #pragma unroll
    for (int ct = 0; ct < 4; ++ct) {
      float cm = colmax[ct * 16 + lr];
      #pragma unroll
      for (int rt = 0; rt < 4; ++rt) {
        float v = expf(lse[rt][ct] - cm);
        if (!(lg & 1))
          ehat[((size_t)bt0 + ct * 16 + lr) * 64 + (w * 8 + rt * 2 + (lg >> 1))] = v;
      }
    }
  }
}

// ---------------- K4: per-chunk product, single fat wave ---------------------
// One 64-lane wave carries the FULL 64-col state as packed bf16.
// r4 fixes: (1) restore e double-buffering (r3 exposed the e-load latency on
// the serial step path); (2) HW cvt_pk for all packs (r1-vs-r2 A/B: >= sw
// pack, ~5x fewer VALU ops at 32 packs/step); (3) setprio(1) around the
// compute cluster (independent 1-wave blocks = T5's winning regime).
__global__ __launch_bounds__(64) void mmm_chunk_kernel(
    const short* __restrict__ WTbf, const float* __restrict__ ehat,
    const float* __restrict__ cmax, float* __restrict__ NT,
    float* __restrict__ aux) {
  int chunk = blockIdx.x, b = blockIdx.y;
  int lane = threadIdx.x;
  int l31 = lane & 31, hi = lane >> 5;

  // A = W^T: af[wi][kb], row = wi*32+l31, k = kb*16 + hi*8 + j (shared by strips)
  bf16x8 af[2][4];
  #pragma unroll
  for (int wi = 0; wi < 2; ++wi)
    #pragma unroll
    for (int kb = 0; kb < 4; ++kb)
      af[wi][kb] = *(const bf16x8*)&WTbf[(wi * 32 + l31) * 64 + kb * 16 + hi * 8];

  // packed state: P[s][cm][q][p] = bf16 rows {32cm+8q+4hi+2p, +1} at col s*32+l31
  unsigned P[2][2][4][2];
  #pragma unroll
  for (int s = 0; s < 2; ++s) {
    int col = s * 32 + l31;
    #pragma unroll
    for (int cm = 0; cm < 2; ++cm)
      #pragma unroll
      for (int q = 0; q < 4; ++q)
        #pragma unroll
        for (int p = 0; p < 2; ++p) {
          int row = 32 * cm + 8 * q + 4 * hi + 2 * p;
          unsigned lo = (row == col) ? 0x3F80u : 0u;       // bf16(1.0)
          unsigned h16 = (row + 1 == col) ? 0x3F80u : 0u;
          P[s][cm][q][p] = lo | (h16 << 16);
        }
  }

  int t0 = (chunk == 0) ? 1 : chunk * 16;
  int nsteps = (chunk == 0) ? 15 : 16;
  const float* eb = ehat + (size_t)b * 4096 * 64;

  float logscale = 0.f;
  f32x4 ecur[2][4], enxt[2][4];
  #pragma unroll
  for (int cm = 0; cm < 2; ++cm)
    #pragma unroll
    for (int q = 0; q < 4; ++q)
      ecur[cm][q] = *(const f32x4*)&eb[(size_t)t0 * 64 + cm * 32 + q * 8 + hi * 4];

  for (int it = 0; it < nsteps; ++it) {
    if (it + 1 < nsteps) {  // prefetch next step's e (issue-early, consume-late)
      #pragma unroll
      for (int cm = 0; cm < 2; ++cm)
        #pragma unroll
        for (int q = 0; q < 4; ++q)
          enxt[cm][q] = *(const f32x4*)&eb[(size_t)(t0 + it + 1) * 64 + cm * 32 + q * 8 + hi * 4];
    }

    __builtin_amdgcn_s_setprio(1);
    #pragma unroll
    for (int s = 0; s < 2; ++s) {
      // B[kb]: k = kb*16 + 8*hi + j; one permlane32_swap per (quad-pair, p)
      bf16x8 B[4];
      #pragma unroll
      for (int kb = 0; kb < 4; ++kb) {
        int cm = kb >> 1, kbl = kb & 1;
        int4 wrd;
        #pragma unroll
        for (int p = 0; p < 2; ++p) {
          unsigned avv = P[s][cm][2 * kbl + 1][p];
          unsigned bvv = P[s][cm][2 * kbl][p];
          asm("v_permlane32_swap_b32 %0, %1" : "+v"(avv), "+v"(bvv));
          if (p == 0) { wrd.x = (int)bvv; wrd.z = (int)avv; }
          else        { wrd.y = (int)bvv; wrd.w = (int)avv; }
        }
        B[kb] = *(bf16x8*)&wrd;
      }

      f32x16 d0, d1;
      #pragma unroll
      for (int r = 0; r < 16; ++r) { d0[r] = 0.f; d1[r] = 0.f; }
      #pragma unroll
      for (int kb = 0; kb < 4; ++kb) {
        d0 = mfma32(af[0][kb], B[kb], d0);
        d1 = mfma32(af[1][kb], B[kb], d1);
      }

      // P = pack(d * e): reg 4q+s_ -> row 32cm+8q+4hi+s_
      #pragma unroll
      for (int q = 0; q < 4; ++q)
        #pragma unroll
        for (int p = 0; p < 2; ++p) {
          P[s][0][q][p] = cvtpk(d0[4 * q + 2 * p] * ecur[0][q][2 * p],
                                d0[4 * q + 2 * p + 1] * ecur[0][q][2 * p + 1]);
          P[s][1][q][p] = cvtpk(d1[4 * q + 2 * p] * ecur[1][q][2 * p],
                                d1[4 * q + 2 * p + 1] * ecur[1][q][2 * p + 1]);
        }
    }
    __builtin_amdgcn_s_setprio(0);

    if ((it & 7) == 7) {  // whole-chunk rescale, applied in place on P
      float m = 0.f;
      #pragma unroll
      for (int s = 0; s < 2; ++s)
        #pragma unroll
        for (int cm = 0; cm < 2; ++cm)
          #pragma unroll
          for (int q = 0; q < 4; ++q)
            #pragma unroll
            for (int p = 0; p < 2; ++p) {
              unsigned u = P[s][cm][q][p];
              m = fmaxf(m, __uint_as_float(u << 16));
              m = fmaxf(m, __uint_as_float(u & 0xffff0000u));
            }
      #pragma unroll
      for (int off = 1; off < 64; off <<= 1) m = fmaxf(m, __shfl_xor(m, off));
      float inv = 1.0f / m;
      #pragma unroll
      for (int s = 0; s < 2; ++s)
        #pragma unroll
        for (int cm = 0; cm < 2; ++cm)
          #pragma unroll
          for (int q = 0; q < 4; ++q)
            #pragma unroll
            for (int p = 0; p < 2; ++p) {
              unsigned u = P[s][cm][q][p];
              P[s][cm][q][p] = cvtpk(__uint_as_float(u << 16) * inv,
                                     __uint_as_float(u & 0xffff0000u) * inv);
            }
      logscale += logf(m);
    }

    #pragma unroll
    for (int cm = 0; cm < 2; ++cm)
      #pragma unroll
      for (int q = 0; q < 4; ++q) ecur[cm][q] = enxt[cm][q];
  }

  // store N_c f32 row-major [row][col] (unpack bf16 state; K5 rounds to bf16
  // anyway, so values are identical to the old f32-carried path)
  float* No = NT + (((size_t)b * 256 + chunk) << 12);
  #pragma unroll
  for (int s = 0; s < 2; ++s)
    #pragma unroll
    for (int cm = 0; cm < 2; ++cm)
      #pragma unroll
      for (int q = 0; q < 4; ++q)
        #pragma unroll
        for (int p = 0; p < 2; ++p) {
          int row = 32 * cm + 8 * q + 4 * hi + 2 * p;
          int col = s * 32 + l31;
          unsigned u = P[s][cm][q][p];
          No[row * 64 + col] = __uint_as_float(u << 16);
          No[(row + 1) * 64 + col] = __uint_as_float(u & 0xffff0000u);
        }

  // aux[b][chunk] = sum cmax + chunk logscale (single scale, whole chunk)
  float cs = (lane < nsteps) ? cmax[(size_t)b * 4096 + t0 + lane] : 0.f;
  #pragma unroll
  for (int off = 1; off < 64; off <<= 1) cs += __shfl_xor(cs, off);
  if (lane == 0) aux[(size_t)b * 256 + chunk] = cs + logscale;
}

// ---------------- K5: merge 16 chunks -> group matrix (16 groups/batch) -----
// Q' = N_cc * Q; N_cc uniformly scaled (single aux scalar per chunk).
__global__ __launch_bounds__(256) void mmm_merge_kernel(
    const float* __restrict__ NT, const float* __restrict__ aux,
    float* __restrict__ G2T, float* __restrict__ auxg) {
  int g = blockIdx.x, b = blockIdx.y;
  int tid = threadIdx.x;
  int w = tid >> 6, lane = tid & 63;
  int wi = w >> 1, wj = w & 1;
  int lr = lane & 15, lg = lane >> 4;

  __shared__ __align__(16) short L[2][4096];
  __shared__ float wmax[4];

  for (int idx = tid; idx < 4096; idx += 256) {
    int j = idx >> 6, k = idx & 63;
    L[0][idx ^ ((j & 7) << 3)] = (j == k) ? (short)0x3F80 : (short)0;
  }
  __syncthreads();

  int cbase = b * 256 + g * 16;

  float logscale = 0.f;
  int cur = 0;
  f32x4 acc[2][2];

  f32x4 apre[2][2][2];
  {
    const float* Mc = NT + ((size_t)cbase << 12);
    #pragma unroll
    for (int rt = 0; rt < 2; ++rt)
      #pragma unroll
      for (int kc = 0; kc < 2; ++kc) {
        const float* src = Mc + (wi * 32 + rt * 16 + lr) * 64 + kc * 32 + lg * 8;
        apre[rt][kc][0] = *(const f32x4*)src;
        apre[rt][kc][1] = *(const f32x4*)(src + 4);
      }
  }

  for (int cc = 0; cc < 16; ++cc) {
    f32x4 acur[2][2][2];
    #pragma unroll
    for (int rt = 0; rt < 2; ++rt)
      #pragma unroll
      for (int kc = 0; kc < 2; ++kc) {
        acur[rt][kc][0] = apre[rt][kc][0];
        acur[rt][kc][1] = apre[rt][kc][1];
      }
    if (cc < 15) {
      const float* Mc = NT + ((size_t)(cbase + cc + 1) << 12);
      #pragma unroll
      for (int rt = 0; rt < 2; ++rt)
        #pragma unroll
        for (int kc = 0; kc < 2; ++kc) {
          const float* src = Mc + (wi * 32 + rt * 16 + lr) * 64 + kc * 32 + lg * 8;
          apre[rt][kc][0] = *(const f32x4*)src;
          apre[rt][kc][1] = *(const f32x4*)(src + 4);
        }
    }

    // single scale per chunk: just accumulate the log
    logscale += aux[cbase + cc];

    bf16x8 afr[2][2];
    #pragma unroll
    for (int rt = 0; rt < 2; ++rt)
      #pragma unroll
      for (int kc = 0; kc < 2; ++kc) {
        unsigned fw[4];
        fw[0] = cvtpk(acur[rt][kc][0][0], acur[rt][kc][0][1]);
        fw[1] = cvtpk(acur[rt][kc][0][2], acur[rt][kc][0][3]);
        fw[2] = cvtpk(acur[rt][kc][1][0], acur[rt][kc][1][1]);
        fw[3] = cvtpk(acur[rt][kc][1][2], acur[rt][kc][1][3]);
        afr[rt][kc] = *(bf16x8*)fw;
      }

    bf16x8 bfr[2][2];
    #pragma unroll
    for (int ct = 0; ct < 2; ++ct) {
      int j = wj * 32 + ct * 16 + lr;
      int sw = (j & 7) << 3;
      #pragma unroll
      for (int kc = 0; kc < 2; ++kc)
        bfr[ct][kc] = *(const bf16x8*)&L[cur][(j * 64 + kc * 32 + lg * 8) ^ sw];
    }

    #pragma unroll
    for (int rt = 0; rt < 2; ++rt)
      #pragma unroll
      for (int ct = 0; ct < 2; ++ct) {
        f32x4 c = {0.f, 0.f, 0.f, 0.f};
        c = mfma16(afr[rt][0], bfr[ct][0], c);
        c = mfma16(afr[rt][1], bfr[ct][1], c);
        acc[rt][ct] = c;
      }

    float m = 0.f;
    #pragma unroll
    for (int rt = 0; rt < 2; ++rt)
      #pragma unroll
      for (int ct = 0; ct < 2; ++ct)
        #pragma unroll
        for (int r = 0; r < 4; ++r) m = fmaxf(m, acc[rt][ct][r]);
    #pragma unroll
    for (int off = 1; off < 64; off <<= 1) m = fmaxf(m, __shfl_xor(m, off));
    if (lane == 0) wmax[w] = m;
    __syncthreads();
    m = fmaxf(fmaxf(wmax[0], wmax[1]), fmaxf(wmax[2], wmax[3]));
    float inv = 1.0f / m;
    #pragma unroll
    for (int rt = 0; rt < 2; ++rt)
      #pragma unroll
      for (int ct = 0; ct < 2; ++ct) acc[rt][ct] *= inv;
    logscale += logf(m);

    int nxt = cur ^ 1;
    unsigned* L32 = (unsigned*)&L[nxt][0];
    #pragma unroll
    for (int rt = 0; rt < 2; ++rt)
      #pragma unroll
      for (int ct = 0; ct < 2; ++ct) {
        int row0 = wi * 32 + rt * 16 + lg * 4;   // 4-aligned
        int col = wj * 32 + ct * 16 + lr;
        int sidx = (col * 64 + row0) ^ ((col & 7) << 3);  // XOR hits bits>=3 only
        L32[(sidx >> 1) + 0] = cvtpk(acc[rt][ct][0], acc[rt][ct][1]);
        L32[(sidx >> 1) + 1] = cvtpk(acc[rt][ct][2], acc[rt][ct][3]);
      }
    __syncthreads();
    cur = nxt;
  }

  float* Mo = G2T + (((size_t)b * 16 + g) << 12);
  #pragma unroll
  for (int rt = 0; rt < 2; ++rt)
    #pragma unroll
    for (int ct = 0; ct < 2; ++ct)
      #pragma unroll
      for (int r = 0; r < 4; ++r) {
        int row = wi * 32 + rt * 16 + lg * 4 + r;
        int col = wj * 32 + ct * 16 + lr;
        Mo[row * 64 + col] = acc[rt][ct][r];
      }

  if (w == 0 && lane == 0) auxg[b * 16 + g] = logscale;
}

// ---------------- K6: final combine (16 group matrices per batch) -----------
__global__ __launch_bounds__(64) void mmm_combine_kernel(
    const float* __restrict__ pi_logits, const float* __restrict__ ehat,
    const float* __restrict__ cmax, const float* __restrict__ G2T,
    const float* __restrict__ auxg, float* __restrict__ out) {
  int b = blockIdx.x, lane = threadIdx.x;
  __shared__ __align__(16) float alds[64];

  float pv = pi_logits[lane];
  float mx = pv;
  #pragma unroll
  for (int off = 1; off < 64; off <<= 1) mx = fmaxf(mx, __shfl_xor(mx, off));
  float pe = expf(pv - mx);
  float ps = pe;
  #pragma unroll
  for (int off = 1; off < 64; off <<= 1) ps += __shfl_xor(ps, off);

  float a = (pe / ps) * ehat[(size_t)b * 4096 * 64 + lane];
  double logtot = (double)cmax[(size_t)b * 4096];
  alds[lane] = a;
  __builtin_amdgcn_wave_barrier();

  for (int g = 0; g < 16; ++g) {
    const float* Mc = G2T + (((size_t)b * 16 + g) << 12) + lane * 64;
    f32x4 a4 = {0.f, 0.f, 0.f, 0.f};
    #pragma unroll
    for (int i = 0; i < 64; i += 4) {
      f32x4 mv = *(const f32x4*)&Mc[i];
      f32x4 av = *(const f32x4*)&alds[i];
      a4 += mv * av;
    }
    float acc = (a4[0] + a4[1]) + (a4[2] + a4[3]);
    float s = acc;
    #pragma unroll
    for (int off = 1; off < 64; off <<= 1) s += __shfl_xor(s, off);
    logtot += (double)(auxg[b * 16 + g] + logf(s));
    float an = acc / s;
    __builtin_amdgcn_wave_barrier();
    alds[lane] = an;
    __builtin_amdgcn_wave_barrier();
  }
  if (lane == 0) out[b] = (float)logtot;
}

extern "C" void kernel_launch(void* const* d_in, const int* in_sizes, int n_in,
                              void* d_out, int out_size, void* d_ws, size_t ws_size,
                              hipStream_t stream) {
  const float* X      = (const float*)d_in[0];
  const float* pi_l   = (const float*)d_in[1];
  const float* tr_l   = (const float*)d_in[2];
  const float* wl     = (const float*)d_in[3];
  const float* means  = (const float*)d_in[4];
  const float* lvs    = (const float*)d_in[5];
  float* out = (float*)d_out;

  float* ws = (float*)d_ws;
  short* Gt      = (short*)ws;                 // 131072 shorts = 65536 f32
  float* const_c = ws + 65536;                 // 512
  short* WTbf    = (short*)(ws + 66048);       // 4096 shorts = 2048 f32
  float* cmaxp   = ws + 68608;                 // 32768
  float* ehat    = ws + 101376;                // 2097152
  short* XeP     = (short*)(ws + 2198528);     // 16 MB
  float* NT      = ws + 2198528;               // aliases XeP (dead after emis); 8388608 f32
  float* aux     = ws + 10587136;              // 2048 (256 chunks x 8 b)
  float* G2T     = ws + 10591232;              // 524288 (8 b x 16 g x 4096)
  float* auxg    = ws + 11115520;              // 128

  mmm_w_kernel<<<64, 64, 0, stream>>>(tr_l, WTbf);
  mmm_prep_kernel<<<512, 128, 0, stream>>>(means, lvs, wl, Gt, const_c);
  mmm_prepxe_kernel<<<512, 256, 0, stream>>>(X, XeP);
  mmm_emis_kernel<<<256, 512, 0, stream>>>(Gt, XeP, const_c, ehat, cmaxp);
  mmm_chunk_kernel<<<dim3(256, 8), 64, 0, stream>>>(WTbf, ehat, cmaxp, NT, aux);
  mmm_merge_kernel<<<dim3(16, 8), 256, 0, stream>>>(NT, aux, G2T, auxg);
  mmm_combine_kernel<<<8, 64, 0, stream>>>(pi_l, ehat, cmaxp, G2T, auxg, out);
}

// Round 5
// 125.787 us; speedup vs baseline: 1.1029x; 1.0184x over previous
//
#include <hip/hip_runtime.h>
#include <hip/hip_bf16.h>
#include <math.h>

#define LOG2PI_F 1.8378770664093453f

typedef __attribute__((ext_vector_type(8))) short bf16x8;
typedef __attribute__((ext_vector_type(4))) float f32x4;
typedef __attribute__((ext_vector_type(16))) float f32x16;

static __device__ inline short f2bf(float x) {
  __hip_bfloat16 h = __float2bfloat16(x);
  return *reinterpret_cast<short*>(&h);
}
// HW packed f32->bf16 (RNE). Within-session A/B (r1 vs r2: 137.6 vs 138.7)
// shows this is >= the software pack here, contra m240's probe: K4/K2/K5 are
// pack-dense (32 packs/step in K4), so the ~5x static VALU saving wins.
static __device__ inline unsigned cvtpk(float lo, float hi) {
  unsigned r;
  asm("v_cvt_pk_bf16_f32 %0, %1, %2" : "=v"(r) : "v"(lo), "v"(hi));
  return r;
}
static __device__ inline f32x4 mfma16(bf16x8 a, bf16x8 b, f32x4 c) {
  return __builtin_amdgcn_mfma_f32_16x16x32_bf16(a, b, c, 0, 0, 0);
}
static __device__ inline f32x16 mfma32(bf16x8 a, bf16x8 b, f32x16 c) {
  return __builtin_amdgcn_mfma_f32_32x32x16_bf16(a, b, c, 0, 0, 0);
}

// ---------------- K0: WTbf[k'][k] = bf16(softmax_row_k(tl)[k']) -------------
__global__ __launch_bounds__(64) void mmm_w_kernel(
    const float* __restrict__ tl, short* __restrict__ WTbf) {
  int r = blockIdx.x, lane = threadIdx.x;
  float v = tl[r * 64 + lane];
  float mx = v;
  #pragma unroll
  for (int off = 1; off < 64; off <<= 1) mx = fmaxf(mx, __shfl_xor(mx, off));
  float e = expf(v - mx);
  float s = e;
  #pragma unroll
  for (int off = 1; off < 64; off <<= 1) s += __shfl_xor(s, off);
  WTbf[lane * 64 + r] = f2bf(e / s);
}

// ---------------- K1: prep Gt bf16 [512][256] + const_c[512] ----------------
__global__ __launch_bounds__(128) void mmm_prep_kernel(
    const float* __restrict__ means, const float* __restrict__ log_vars,
    const float* __restrict__ weight_logits,
    short* __restrict__ Gt, float* __restrict__ const_c) {
  int sm = blockIdx.x;
  int s = sm >> 3, m = sm & 7;
  int d = threadIdx.x;
  float lv = log_vars[sm * 128 + d];
  float iv = expf(-lv);
  float mu = means[sm * 128 + d];
  float miv = mu * iv;
  Gt[sm * 256 + d] = f2bf(miv);
  Gt[sm * 256 + 128 + d] = f2bf(-0.5f * iv);
  float v = mu * miv + lv;
  #pragma unroll
  for (int off = 1; off < 64; off <<= 1) v += __shfl_xor(v, off);
  __shared__ float red[2];
  if ((d & 63) == 0) red[d >> 6] = v;
  __syncthreads();
  if (d == 0) {
    float tot = red[0] + red[1];
    float wl[8];
    float mx = -3.4e38f;
    #pragma unroll
    for (int j = 0; j < 8; ++j) { wl[j] = weight_logits[s * 8 + j]; mx = fmaxf(mx, wl[j]); }
    float sum = 0.f;
    #pragma unroll
    for (int j = 0; j < 8; ++j) sum += expf(wl[j] - mx);
    float lmw = wl[m] - mx - logf(sum);
    const_c[sm] = -0.5f * (tot + 128.0f * LOG2PI_F) + lmw;
  }
}

// ---------------- K2: prep XeP bf16 packed [8 kb2][32768 bt][32 kk] ----------
__global__ __launch_bounds__(256) void mmm_prepxe_kernel(
    const float* __restrict__ X, short* __restrict__ XeP) {
  int q = blockIdx.x >> 7;
  int bt = ((blockIdx.x & 127) << 8) + threadIdx.x;
  const float4* src = (const float4*)(X + (size_t)bt * 128 + q * 32);
  float xv[32];
  #pragma unroll
  for (int i = 0; i < 8; ++i) {
    float4 v = src[i];
    xv[4 * i] = v.x; xv[4 * i + 1] = v.y; xv[4 * i + 2] = v.z; xv[4 * i + 3] = v.w;
  }
  size_t base1 = ((size_t)q * 32768 + bt) * 32;
  size_t base2 = ((size_t)(q + 4) * 32768 + bt) * 32;
  int bx = bt & 3;
  #pragma unroll
  for (int g = 0; g < 4; ++g) {
    unsigned w1[4], w2[4];
    #pragma unroll
    for (int j = 0; j < 4; ++j) {
      float a = xv[g * 8 + 2 * j], c = xv[g * 8 + 2 * j + 1];
      w1[j] = cvtpk(a, c);
      w2[j] = cvtpk(a * a, c * c);
    }
    int gs = (g ^ bx) * 8;
    *(uint4*)&XeP[base1 + gs] = *(uint4*)w1;
    *(uint4*)&XeP[base2 + gs] = *(uint4*)w2;
  }
}

// ---------------- K3: MFMA emission GEMM, C[sm=512][bt=64-tile] ------------
__global__ __launch_bounds__(512) void mmm_emis_kernel(
    const short* __restrict__ Gt, const short* __restrict__ XeP,
    const float* __restrict__ const_c,
    float* __restrict__ ehat, float* __restrict__ cmax) {
  __shared__ __align__(16) short Bt[16384];  // 32 KB
  __shared__ __align__(16) float ccs[512];
  __shared__ float wavemax[8][64];
  __shared__ float colmax[64];
  int tid = threadIdx.x;
  int w = tid >> 6, lane = tid & 63, lr = lane & 15, lg = lane >> 4;

  ccs[tid] = const_c[tid];

  bf16x8 gf[4][8];
  #pragma unroll
  for (int rt = 0; rt < 4; ++rt) {
    int row = w * 64 + rt * 16 + lr;
    #pragma unroll
    for (int kc = 0; kc < 8; ++kc)
      gf[rt][kc] = *(const bf16x8*)&Gt[row * 256 + kc * 32 + lg * 8];
  }

  uint4 sreg[4];
  {
    size_t bt0 = (size_t)blockIdx.x * 64;
    #pragma unroll
    for (int r = 0; r < 4; ++r) {
      int ofs = r * 8192 + tid * 16;
      int kb2 = ofs >> 12, rem = ofs & 4095;
      sreg[r] = *(const uint4*)((const char*)XeP + ((size_t)kb2 * 32768 + bt0) * 64 + rem);
    }
  }

  for (int it = 0; it < 2; ++it) {
    int bt0 = (blockIdx.x + it * 256) * 64;
    __syncthreads();
    #pragma unroll
    for (int r = 0; r < 4; ++r)
      *(uint4*)((char*)Bt + r * 8192 + tid * 16) = sreg[r];
    __syncthreads();
    if (it == 0) {
      size_t bt0n = ((size_t)blockIdx.x + 256) * 64;
      #pragma unroll
      for (int r = 0; r < 4; ++r) {
        int ofs = r * 8192 + tid * 16;
        int kb2 = ofs >> 12, rem = ofs & 4095;
        sreg[r] = *(const uint4*)((const char*)XeP + ((size_t)kb2 * 32768 + bt0n) * 64 + rem);
      }
    }

    f32x4 acc[4][4];
    #pragma unroll
    for (int rt = 0; rt < 4; ++rt)
      #pragma unroll
      for (int ct = 0; ct < 4; ++ct)
        acc[rt][ct] = (f32x4){0.f, 0.f, 0.f, 0.f};

    #pragma unroll
    for (int kc = 0; kc < 8; ++kc) {
      bf16x8 bfr[4];
      #pragma unroll
      for (int ct = 0; ct < 4; ++ct) {
        int btL = ct * 16 + lr;
        bfr[ct] = *(const bf16x8*)&Bt[kc * 2048 + btL * 32 + ((lg ^ (btL & 3)) * 8)];
      }
      #pragma unroll
      for (int rt = 0; rt < 4; ++rt)
        #pragma unroll
        for (int ct = 0; ct < 4; ++ct)
          acc[rt][ct] = mfma16(gf[rt][kc], bfr[ct], acc[rt][ct]);
    }

    float lse[4][4];
    #pragma unroll
    for (int rt = 0; rt < 4; ++rt) {
      f32x4 cc = *(f32x4*)&ccs[w * 64 + rt * 16 + lg * 4];
      #pragma unroll
      for (int ct = 0; ct < 4; ++ct) {
        f32x4 v = acc[rt][ct] + cc;
        float mx = fmaxf(fmaxf(v[0], v[1]), fmaxf(v[2], v[3]));
        mx = fmaxf(mx, __shfl_xor(mx, 16));
        float sum = expf(v[0] - mx) + expf(v[1] - mx) + expf(v[2] - mx) + expf(v[3] - mx);
        sum += __shfl_xor(sum, 16);
        lse[rt][ct] = mx + logf(sum);
      }
    }
    #pragma unroll
    for (int ct = 0; ct < 4; ++ct) {
      float cm = fmaxf(fmaxf(lse[0][ct], lse[1][ct]), fmaxf(lse[2][ct], lse[3][ct]));
      cm = fmaxf(cm, __shfl_xor(cm, 32));
      if (lg == 0) wavemax[w][ct * 16 + lr] = cm;
    }
    __syncthreads();
    if (w == 0) {
      float cm = wavemax[0][lane];
      #pragma unroll
      for (int ww = 1; ww < 8; ++ww) cm = fmaxf(cm, wavemax[ww][lane]);
      colmax[lane] = cm;
      cmax[(size_t)bt0 + lane] = cm;
    }
    __syncthreads();
    #pragma unroll
    for (int ct = 0; ct < 4; ++ct) {
      float cm = colmax[ct * 16 + lr];
      #pragma unroll
      for (int rt = 0; rt < 4; ++rt) {
        float v = expf(lse[rt][ct] - cm);
        if (!(lg & 1))
          ehat[((size_t)bt0 + ct * 16 + lr) * 64 + (w * 8 + rt * 2 + (lg >> 1))] = v;
      }
    }
  }
}

// ---------------- K4: per-chunk product, single fat wave ---------------------
// One 64-lane wave carries the FULL 64-col state as packed bf16.
// r5 fix: stage the chunk's whole e-slice (16 rows x 64 f32 = 4KB, contiguous)
// into LDS up-front with 4 coalesced dwordx4/lane. Rationale: per-step global
// e-loads are cold (each 4KB ehat slice read once; HBM-miss ~900cy) and the
// ~200cy step compute + 1-step prefetch cannot cover them -> ~700cy exposed
// stall per step was the dominant K4 term. LDS pays the latency once; the
// step loop double-buffers from LDS (ds_read ~120cy, fully covered).
__global__ __launch_bounds__(64) void mmm_chunk_kernel(
    const short* __restrict__ WTbf, const float* __restrict__ ehat,
    const float* __restrict__ cmax, float* __restrict__ NT,
    float* __restrict__ aux) {
  __shared__ __align__(16) float elds[1024];  // 16 steps x 64 rows
  int chunk = blockIdx.x, b = blockIdx.y;
  int lane = threadIdx.x;
  int l31 = lane & 31, hi = lane >> 5;

  int t0 = (chunk == 0) ? 1 : chunk * 16;
  int nsteps = (chunk == 0) ? 15 : 16;
  const float* eb = ehat + (size_t)b * 4096 * 64;

  // stage e-slice first (issue-early): rows t0..t0+15 are always in-bounds
  {
    const float* esrc = eb + (size_t)t0 * 64;
    #pragma unroll
    for (int r = 0; r < 4; ++r)
      *(f32x4*)&elds[r * 256 + lane * 4] = *(const f32x4*)&esrc[r * 256 + lane * 4];
  }

  // A = W^T: af[wi][kb], row = wi*32+l31, k = kb*16 + hi*8 + j (shared by strips)
  bf16x8 af[2][4];
  #pragma unroll
  for (int wi = 0; wi < 2; ++wi)
    #pragma unroll
    for (int kb = 0; kb < 4; ++kb)
      af[wi][kb] = *(const bf16x8*)&WTbf[(wi * 32 + l31) * 64 + kb * 16 + hi * 8];

  // packed state: P[s][cm][q][p] = bf16 rows {32cm+8q+4hi+2p, +1} at col s*32+l31
  unsigned P[2][2][4][2];
  #pragma unroll
  for (int s = 0; s < 2; ++s) {
    int col = s * 32 + l31;
    #pragma unroll
    for (int cm = 0; cm < 2; ++cm)
      #pragma unroll
      for (int q = 0; q < 4; ++q)
        #pragma unroll
        for (int p = 0; p < 2; ++p) {
          int row = 32 * cm + 8 * q + 4 * hi + 2 * p;
          unsigned lo = (row == col) ? 0x3F80u : 0u;       // bf16(1.0)
          unsigned h16 = (row + 1 == col) ? 0x3F80u : 0u;
          P[s][cm][q][p] = lo | (h16 << 16);
        }
  }

  __syncthreads();  // e-slice visible wave-wide

  float logscale = 0.f;
  f32x4 ecur[2][4], enxt[2][4];
  #pragma unroll
  for (int cm = 0; cm < 2; ++cm)
    #pragma unroll
    for (int q = 0; q < 4; ++q)
      ecur[cm][q] = *(const f32x4*)&elds[cm * 32 + q * 8 + hi * 4];

  for (int it = 0; it < nsteps; ++it) {
    if (it + 1 < nsteps) {  // prefetch next step's e from LDS
      #pragma unroll
      for (int cm = 0; cm < 2; ++cm)
        #pragma unroll
        for (int q = 0; q < 4; ++q)
          enxt[cm][q] = *(const f32x4*)&elds[(it + 1) * 64 + cm * 32 + q * 8 + hi * 4];
    }

    __builtin_amdgcn_s_setprio(1);
    #pragma unroll
    for (int s = 0; s < 2; ++s) {
      // B[kb]: k = kb*16 + 8*hi + j; one permlane32_swap per (quad-pair, p)
      bf16x8 B[4];
      #pragma unroll
      for (int kb = 0; kb < 4; ++kb) {
        int cm = kb >> 1, kbl = kb & 1;
        int4 wrd;
        #pragma unroll
        for (int p = 0; p < 2; ++p) {
          unsigned avv = P[s][cm][2 * kbl + 1][p];
          unsigned bvv = P[s][cm][2 * kbl][p];
          asm("v_permlane32_swap_b32 %0, %1" : "+v"(avv), "+v"(bvv));
          if (p == 0) { wrd.x = (int)bvv; wrd.z = (int)avv; }
          else        { wrd.y = (int)bvv; wrd.w = (int)avv; }
        }
        B[kb] = *(bf16x8*)&wrd;
      }

      f32x16 d0, d1;
      #pragma unroll
      for (int r = 0; r < 16; ++r) { d0[r] = 0.f; d1[r] = 0.f; }
      #pragma unroll
      for (int kb = 0; kb < 4; ++kb) {
        d0 = mfma32(af[0][kb], B[kb], d0);
        d1 = mfma32(af[1][kb], B[kb], d1);
      }

      // P = pack(d * e): reg 4q+s_ -> row 32cm+8q+4hi+s_
      #pragma unroll
      for (int q = 0; q < 4; ++q)
        #pragma unroll
        for (int p = 0; p < 2; ++p) {
          P[s][0][q][p] = cvtpk(d0[4 * q + 2 * p] * ecur[0][q][2 * p],
                                d0[4 * q + 2 * p + 1] * ecur[0][q][2 * p + 1]);
          P[s][1][q][p] = cvtpk(d1[4 * q + 2 * p] * ecur[1][q][2 * p],
                                d1[4 * q + 2 * p + 1] * ecur[1][q][2 * p + 1]);
        }
    }
    __builtin_amdgcn_s_setprio(0);

    if ((it & 7) == 7) {  // whole-chunk rescale, applied in place on P
      float m = 0.f;
      #pragma unroll
      for (int s = 0; s < 2; ++s)
        #pragma unroll
        for (int cm = 0; cm < 2; ++cm)
          #pragma unroll
          for (int q = 0; q < 4; ++q)
            #pragma unroll
            for (int p = 0; p < 2; ++p) {
              unsigned u = P[s][cm][q][p];
              m = fmaxf(m, __uint_as_float(u << 16));
              m = fmaxf(m, __uint_as_float(u & 0xffff0000u));
            }
      #pragma unroll
      for (int off = 1; off < 64; off <<= 1) m = fmaxf(m, __shfl_xor(m, off));
      float inv = 1.0f / m;
      #pragma unroll
      for (int s = 0; s < 2; ++s)
        #pragma unroll
        for (int cm = 0; cm < 2; ++cm)
          #pragma unroll
          for (int q = 0; q < 4; ++q)
            #pragma unroll
            for (int p = 0; p < 2; ++p) {
              unsigned u = P[s][cm][q][p];
              P[s][cm][q][p] = cvtpk(__uint_as_float(u << 16) * inv,
                                     __uint_as_float(u & 0xffff0000u) * inv);
            }
      logscale += logf(m);
    }

    #pragma unroll
    for (int cm = 0; cm < 2; ++cm)
      #pragma unroll
      for (int q = 0; q < 4; ++q) ecur[cm][q] = enxt[cm][q];
  }

  // store N_c f32 row-major [row][col] (unpack bf16 state; K5 rounds to bf16
  // anyway, so values are identical to the old f32-carried path)
  float* No = NT + (((size_t)b * 256 + chunk) << 12);
  #pragma unroll
  for (int s = 0; s < 2; ++s)
    #pragma unroll
    for (int cm = 0; cm < 2; ++cm)
      #pragma unroll
      for (int q = 0; q < 4; ++q)
        #pragma unroll
        for (int p = 0; p < 2; ++p) {
          int row = 32 * cm + 8 * q + 4 * hi + 2 * p;
          int col = s * 32 + l31;
          unsigned u = P[s][cm][q][p];
          No[row * 64 + col] = __uint_as_float(u << 16);
          No[(row + 1) * 64 + col] = __uint_as_float(u & 0xffff0000u);
        }

  // aux[b][chunk] = sum cmax + chunk logscale (single scale, whole chunk)
  float cs = (lane < nsteps) ? cmax[(size_t)b * 4096 + t0 + lane] : 0.f;
  #pragma unroll
  for (int off = 1; off < 64; off <<= 1) cs += __shfl_xor(cs, off);
  if (lane == 0) aux[(size_t)b * 256 + chunk] = cs + logscale;
}

// ---------------- K5: merge 16 chunks -> group matrix (16 groups/batch) -----
// Q' = N_cc * Q; N_cc uniformly scaled (single aux scalar per chunk).
__global__ __launch_bounds__(256) void mmm_merge_kernel(
    const float* __restrict__ NT, const float* __restrict__ aux,
    float* __restrict__ G2T, float* __restrict__ auxg) {
  int g = blockIdx.x, b = blockIdx.y;
  int tid = threadIdx.x;
  int w = tid >> 6, lane = tid & 63;
  int wi = w >> 1, wj = w & 1;
  int lr = lane & 15, lg = lane >> 4;

  __shared__ __align__(16) short L[2][4096];
  __shared__ float wmax[4];

  for (int idx = tid; idx < 4096; idx += 256) {
    int j = idx >> 6, k = idx & 63;
    L[0][idx ^ ((j & 7) << 3)] = (j == k) ? (short)0x3F80 : (short)0;
  }
  __syncthreads();

  int cbase = b * 256 + g * 16;

  float logscale = 0.f;
  int cur = 0;
  f32x4 acc[2][2];

  f32x4 apre[2][2][2];
  {
    const float* Mc = NT + ((size_t)cbase << 12);
    #pragma unroll
    for (int rt = 0; rt < 2; ++rt)
      #pragma unroll
      for (int kc = 0; kc < 2; ++kc) {
        const float* src = Mc + (wi * 32 + rt * 16 + lr) * 64 + kc * 32 + lg * 8;
        apre[rt][kc][0] = *(const f32x4*)src;
        apre[rt][kc][1] = *(const f32x4*)(src + 4);
      }
  }

  for (int cc = 0; cc < 16; ++cc) {
    f32x4 acur[2][2][2];
    #pragma unroll
    for (int rt = 0; rt < 2; ++rt)
      #pragma unroll
      for (int kc = 0; kc < 2; ++kc) {
        acur[rt][kc][0] = apre[rt][kc][0];
        acur[rt][kc][1] = apre[rt][kc][1];
      }
    if (cc < 15) {
      const float* Mc = NT + ((size_t)(cbase + cc + 1) << 12);
      #pragma unroll
      for (int rt = 0; rt < 2; ++rt)
        #pragma unroll
        for (int kc = 0; kc < 2; ++kc) {
          const float* src = Mc + (wi * 32 + rt * 16 + lr) * 64 + kc * 32 + lg * 8;
          apre[rt][kc][0] = *(const f32x4*)src;
          apre[rt][kc][1] = *(const f32x4*)(src + 4);
        }
    }

    // single scale per chunk: just accumulate the log
    logscale += aux[cbase + cc];

    bf16x8 afr[2][2];
    #pragma unroll
    for (int rt = 0; rt < 2; ++rt)
      #pragma unroll
      for (int kc = 0; kc < 2; ++kc) {
        unsigned fw[4];
        fw[0] = cvtpk(acur[rt][kc][0][0], acur[rt][kc][0][1]);
        fw[1] = cvtpk(acur[rt][kc][0][2], acur[rt][kc][0][3]);
        fw[2] = cvtpk(acur[rt][kc][1][0], acur[rt][kc][1][1]);
        fw[3] = cvtpk(acur[rt][kc][1][2], acur[rt][kc][1][3]);
        afr[rt][kc] = *(bf16x8*)fw;
      }

    bf16x8 bfr[2][2];
    #pragma unroll
    for (int ct = 0; ct < 2; ++ct) {
      int j = wj * 32 + ct * 16 + lr;
      int sw = (j & 7) << 3;
      #pragma unroll
      for (int kc = 0; kc < 2; ++kc)
        bfr[ct][kc] = *(const bf16x8*)&L[cur][(j * 64 + kc * 32 + lg * 8) ^ sw];
    }

    #pragma unroll
    for (int rt = 0; rt < 2; ++rt)
      #pragma unroll
      for (int ct = 0; ct < 2; ++ct) {
        f32x4 c = {0.f, 0.f, 0.f, 0.f};
        c = mfma16(afr[rt][0], bfr[ct][0], c);
        c = mfma16(afr[rt][1], bfr[ct][1], c);
        acc[rt][ct] = c;
      }

    float m = 0.f;
    #pragma unroll
    for (int rt = 0; rt < 2; ++rt)
      #pragma unroll
      for (int ct = 0; ct < 2; ++ct)
        #pragma unroll
        for (int r = 0; r < 4; ++r) m = fmaxf(m, acc[rt][ct][r]);
    #pragma unroll
    for (int off = 1; off < 64; off <<= 1) m = fmaxf(m, __shfl_xor(m, off));
    if (lane == 0) wmax[w] = m;
    __syncthreads();
    m = fmaxf(fmaxf(wmax[0], wmax[1]), fmaxf(wmax[2], wmax[3]));
    float inv = 1.0f / m;
    #pragma unroll
    for (int rt = 0; rt < 2; ++rt)
      #pragma unroll
      for (int ct = 0; ct < 2; ++ct) acc[rt][ct] *= inv;
    logscale += logf(m);

    int nxt = cur ^ 1;
    unsigned* L32 = (unsigned*)&L[nxt][0];
    #pragma unroll
    for (int rt = 0; rt < 2; ++rt)
      #pragma unroll
      for (int ct = 0; ct < 2; ++ct) {
        int row0 = wi * 32 + rt * 16 + lg * 4;   // 4-aligned
        int col = wj * 32 + ct * 16 + lr;
        int sidx = (col * 64 + row0) ^ ((col & 7) << 3);  // XOR hits bits>=3 only
        L32[(sidx >> 1) + 0] = cvtpk(acc[rt][ct][0], acc[rt][ct][1]);
        L32[(sidx >> 1) + 1] = cvtpk(acc[rt][ct][2], acc[rt][ct][3]);
      }
    __syncthreads();
    cur = nxt;
  }

  float* Mo = G2T + (((size_t)b * 16 + g) << 12);
  #pragma unroll
  for (int rt = 0; rt < 2; ++rt)
    #pragma unroll
    for (int ct = 0; ct < 2; ++ct)
      #pragma unroll
      for (int r = 0; r < 4; ++r) {
        int row = wi * 32 + rt * 16 + lg * 4 + r;
        int col = wj * 32 + ct * 16 + lr;
        Mo[row * 64 + col] = acc[rt][ct][r];
      }

  if (w == 0 && lane == 0) auxg[b * 16 + g] = logscale;
}

// ---------------- K6: final combine (16 group matrices per batch) -----------
__global__ __launch_bounds__(64) void mmm_combine_kernel(
    const float* __restrict__ pi_logits, const float* __restrict__ ehat,
    const float* __restrict__ cmax, const float* __restrict__ G2T,
    const float* __restrict__ auxg, float* __restrict__ out) {
  int b = blockIdx.x, lane = threadIdx.x;
  __shared__ __align__(16) float alds[64];

  float pv = pi_logits[lane];
  float mx = pv;
  #pragma unroll
  for (int off = 1; off < 64; off <<= 1) mx = fmaxf(mx, __shfl_xor(mx, off));
  float pe = expf(pv - mx);
  float ps = pe;
  #pragma unroll
  for (int off = 1; off < 64; off <<= 1) ps += __shfl_xor(ps, off);

  float a = (pe / ps) * ehat[(size_t)b * 4096 * 64 + lane];
  double logtot = (double)cmax[(size_t)b * 4096];
  alds[lane] = a;
  __builtin_amdgcn_wave_barrier();

  for (int g = 0; g < 16; ++g) {
    const float* Mc = G2T + (((size_t)b * 16 + g) << 12) + lane * 64;
    f32x4 a4 = {0.f, 0.f, 0.f, 0.f};
    #pragma unroll
    for (int i = 0; i < 64; i += 4) {
      f32x4 mv = *(const f32x4*)&Mc[i];
      f32x4 av = *(const f32x4*)&alds[i];
      a4 += mv * av;
    }
    float acc = (a4[0] + a4[1]) + (a4[2] + a4[3]);
    float s = acc;
    #pragma unroll
    for (int off = 1; off < 64; off <<= 1) s += __shfl_xor(s, off);
    logtot += (double)(auxg[b * 16 + g] + logf(s));
    float an = acc / s;
    __builtin_amdgcn_wave_barrier();
    alds[lane] = an;
    __builtin_amdgcn_wave_barrier();
  }
  if (lane == 0) out[b] = (float)logtot;
}

extern "C" void kernel_launch(void* const* d_in, const int* in_sizes, int n_in,
                              void* d_out, int out_size, void* d_ws, size_t ws_size,
                              hipStream_t stream) {
  const float* X      = (const float*)d_in[0];
  const float* pi_l   = (const float*)d_in[1];
  const float* tr_l   = (const float*)d_in[2];
  const float* wl     = (const float*)d_in[3];
  const float* means  = (const float*)d_in[4];
  const float* lvs    = (const float*)d_in[5];
  float* out = (float*)d_out;

  float* ws = (float*)d_ws;
  short* Gt      = (short*)ws;                 // 131072 shorts = 65536 f32
  float* const_c = ws + 65536;                 // 512
  short* WTbf    = (short*)(ws + 66048);       // 4096 shorts = 2048 f32
  float* cmaxp   = ws + 68608;                 // 32768
  float* ehat    = ws + 101376;                // 2097152
  short* XeP     = (short*)(ws + 2198528);     // 16 MB
  float* NT      = ws + 2198528;               // aliases XeP (dead after emis); 8388608 f32
  float* aux     = ws + 10587136;              // 2048 (256 chunks x 8 b)
  float* G2T     = ws + 10591232;              // 524288 (8 b x 16 g x 4096)
  float* auxg    = ws + 11115520;              // 128

  mmm_w_kernel<<<64, 64, 0, stream>>>(tr_l, WTbf);
  mmm_prep_kernel<<<512, 128, 0, stream>>>(means, lvs, wl, Gt, const_c);
  mmm_prepxe_kernel<<<512, 256, 0, stream>>>(X, XeP);
  mmm_emis_kernel<<<256, 512, 0, stream>>>(Gt, XeP, const_c, ehat, cmaxp);
  mmm_chunk_kernel<<<dim3(256, 8), 64, 0, stream>>>(WTbf, ehat, cmaxp, NT, aux);
  mmm_merge_kernel<<<dim3(16, 8), 256, 0, stream>>>(NT, aux, G2T, auxg);
  mmm_combine_kernel<<<8, 64, 0, stream>>>(pi_l, ehat, cmaxp, G2T, auxg, out);
}

// Round 6
// 112.836 us; speedup vs baseline: 1.2295x; 1.1148x over previous
//
#include <hip/hip_runtime.h>
#include <hip/hip_bf16.h>
#include <math.h>

#define LOG2PI_F 1.8378770664093453f

typedef __attribute__((ext_vector_type(8))) short bf16x8;
typedef __attribute__((ext_vector_type(4))) float f32x4;
typedef __attribute__((ext_vector_type(16))) float f32x16;

static __device__ inline short f2bf(float x) {
  __hip_bfloat16 h = __float2bfloat16(x);
  return *reinterpret_cast<short*>(&h);
}
// HW packed f32->bf16 (RNE). Session A/B (r1 vs r2) showed >= sw pack here.
static __device__ inline unsigned cvtpk(float lo, float hi) {
  unsigned r;
  asm("v_cvt_pk_bf16_f32 %0, %1, %2" : "=v"(r) : "v"(lo), "v"(hi));
  return r;
}
static __device__ inline f32x4 mfma16(bf16x8 a, bf16x8 b, f32x4 c) {
  return __builtin_amdgcn_mfma_f32_16x16x32_bf16(a, b, c, 0, 0, 0);
}
static __device__ inline f32x16 mfma32(bf16x8 a, bf16x8 b, f32x16 c) {
  return __builtin_amdgcn_mfma_f32_32x32x16_bf16(a, b, c, 0, 0, 0);
}

// ---------------- K012: fused prep (WTbf + Gt/const_c + XeP) ----------------
// bid 0..63     : K0  WTbf[k'][k] = bf16(softmax_row_k(tl)[k'])   (wave 0 only)
// bid 64..319   : K1  two sm per block (h = tid>>7), Gt + const_c
// bid 320..831  : K2  XeP bf16 packed [8 kb2][32768 bt][32 kk]
__global__ __launch_bounds__(256) void mmm_prep_fused(
    const float* __restrict__ tl, const float* __restrict__ means,
    const float* __restrict__ log_vars, const float* __restrict__ weight_logits,
    const float* __restrict__ X,
    short* __restrict__ WTbf, short* __restrict__ Gt,
    float* __restrict__ const_c, short* __restrict__ XeP) {
  __shared__ float red[4];
  int bid = blockIdx.x;
  int tid = threadIdx.x;

  if (bid < 64) {               // ---- K0 ----
    if (tid < 64) {
      int r = bid, lane = tid;
      float v = tl[r * 64 + lane];
      float mx = v;
      #pragma unroll
      for (int off = 1; off < 64; off <<= 1) mx = fmaxf(mx, __shfl_xor(mx, off));
      float e = expf(v - mx);
      float s = e;
      #pragma unroll
      for (int off = 1; off < 64; off <<= 1) s += __shfl_xor(s, off);
      WTbf[lane * 64 + r] = f2bf(e / s);
    }
    return;
  }

  if (bid < 320) {              // ---- K1 (2 sm per block) ----
    int h = tid >> 7, d = tid & 127;
    int sm = (bid - 64) * 2 + h;
    int s = sm >> 3, m = sm & 7;
    float lv = log_vars[sm * 128 + d];
    float iv = expf(-lv);
    float mu = means[sm * 128 + d];
    float miv = mu * iv;
    Gt[sm * 256 + d] = f2bf(miv);
    Gt[sm * 256 + 128 + d] = f2bf(-0.5f * iv);
    float v = mu * miv + lv;
    #pragma unroll
    for (int off = 1; off < 64; off <<= 1) v += __shfl_xor(v, off);
    if ((tid & 63) == 0) red[tid >> 6] = v;
    __syncthreads();
    if (d == 0) {
      float tot = red[2 * h] + red[2 * h + 1];
      float wl[8];
      float mx = -3.4e38f;
      #pragma unroll
      for (int j = 0; j < 8; ++j) { wl[j] = weight_logits[s * 8 + j]; mx = fmaxf(mx, wl[j]); }
      float sum = 0.f;
      #pragma unroll
      for (int j = 0; j < 8; ++j) sum += expf(wl[j] - mx);
      float lmw = wl[m] - mx - logf(sum);
      const_c[sm] = -0.5f * (tot + 128.0f * LOG2PI_F) + lmw;
    }
    return;
  }

  // ---- K2 ----
  int kbid = bid - 320;
  int q = kbid >> 7;
  int bt = ((kbid & 127) << 8) + tid;
  const float4* src = (const float4*)(X + (size_t)bt * 128 + q * 32);
  float xv[32];
  #pragma unroll
  for (int i = 0; i < 8; ++i) {
    float4 v = src[i];
    xv[4 * i] = v.x; xv[4 * i + 1] = v.y; xv[4 * i + 2] = v.z; xv[4 * i + 3] = v.w;
  }
  size_t base1 = ((size_t)q * 32768 + bt) * 32;
  size_t base2 = ((size_t)(q + 4) * 32768 + bt) * 32;
  int bx = bt & 3;
  #pragma unroll
  for (int g = 0; g < 4; ++g) {
    unsigned w1[4], w2[4];
    #pragma unroll
    for (int j = 0; j < 4; ++j) {
      float a = xv[g * 8 + 2 * j], c = xv[g * 8 + 2 * j + 1];
      w1[j] = cvtpk(a, c);
      w2[j] = cvtpk(a * a, c * c);
    }
    int gs = (g ^ bx) * 8;
    *(uint4*)&XeP[base1 + gs] = *(uint4*)w1;
    *(uint4*)&XeP[base2 + gs] = *(uint4*)w2;
  }
}

// ---------------- K3: MFMA emission GEMM, C[sm=512][bt=64-tile] ------------
__global__ __launch_bounds__(512) void mmm_emis_kernel(
    const short* __restrict__ Gt, const short* __restrict__ XeP,
    const float* __restrict__ const_c,
    float* __restrict__ ehat, float* __restrict__ cmax) {
  __shared__ __align__(16) short Bt[16384];  // 32 KB
  __shared__ __align__(16) float ccs[512];
  __shared__ float wavemax[8][64];
  __shared__ float colmax[64];
  int tid = threadIdx.x;
  int w = tid >> 6, lane = tid & 63, lr = lane & 15, lg = lane >> 4;

  ccs[tid] = const_c[tid];

  bf16x8 gf[4][8];
  #pragma unroll
  for (int rt = 0; rt < 4; ++rt) {
    int row = w * 64 + rt * 16 + lr;
    #pragma unroll
    for (int kc = 0; kc < 8; ++kc)
      gf[rt][kc] = *(const bf16x8*)&Gt[row * 256 + kc * 32 + lg * 8];
  }

  uint4 sreg[4];
  {
    size_t bt0 = (size_t)blockIdx.x * 64;
    #pragma unroll
    for (int r = 0; r < 4; ++r) {
      int ofs = r * 8192 + tid * 16;
      int kb2 = ofs >> 12, rem = ofs & 4095;
      sreg[r] = *(const uint4*)((const char*)XeP + ((size_t)kb2 * 32768 + bt0) * 64 + rem);
    }
  }

  for (int it = 0; it < 2; ++it) {
    int bt0 = (blockIdx.x + it * 256) * 64;
    __syncthreads();
    #pragma unroll
    for (int r = 0; r < 4; ++r)
      *(uint4*)((char*)Bt + r * 8192 + tid * 16) = sreg[r];
    __syncthreads();
    if (it == 0) {
      size_t bt0n = ((size_t)blockIdx.x + 256) * 64;
      #pragma unroll
      for (int r = 0; r < 4; ++r) {
        int ofs = r * 8192 + tid * 16;
        int kb2 = ofs >> 12, rem = ofs & 4095;
        sreg[r] = *(const uint4*)((const char*)XeP + ((size_t)kb2 * 32768 + bt0n) * 64 + rem);
      }
    }

    f32x4 acc[4][4];
    #pragma unroll
    for (int rt = 0; rt < 4; ++rt)
      #pragma unroll
      for (int ct = 0; ct < 4; ++ct)
        acc[rt][ct] = (f32x4){0.f, 0.f, 0.f, 0.f};

    #pragma unroll
    for (int kc = 0; kc < 8; ++kc) {
      bf16x8 bfr[4];
      #pragma unroll
      for (int ct = 0; ct < 4; ++ct) {
        int btL = ct * 16 + lr;
        bfr[ct] = *(const bf16x8*)&Bt[kc * 2048 + btL * 32 + ((lg ^ (btL & 3)) * 8)];
      }
      #pragma unroll
      for (int rt = 0; rt < 4; ++rt)
        #pragma unroll
        for (int ct = 0; ct < 4; ++ct)
          acc[rt][ct] = mfma16(gf[rt][kc], bfr[ct], acc[rt][ct]);
    }

    float lse[4][4];
    #pragma unroll
    for (int rt = 0; rt < 4; ++rt) {
      f32x4 cc = *(f32x4*)&ccs[w * 64 + rt * 16 + lg * 4];
      #pragma unroll
      for (int ct = 0; ct < 4; ++ct) {
        f32x4 v = acc[rt][ct] + cc;
        float mx = fmaxf(fmaxf(v[0], v[1]), fmaxf(v[2], v[3]));
        mx = fmaxf(mx, __shfl_xor(mx, 16));
        float sum = expf(v[0] - mx) + expf(v[1] - mx) + expf(v[2] - mx) + expf(v[3] - mx);
        sum += __shfl_xor(sum, 16);
        lse[rt][ct] = mx + logf(sum);
      }
    }
    #pragma unroll
    for (int ct = 0; ct < 4; ++ct) {
      float cm = fmaxf(fmaxf(lse[0][ct], lse[1][ct]), fmaxf(lse[2][ct], lse[3][ct]));
      cm = fmaxf(cm, __shfl_xor(cm, 32));
      if (lg == 0) wavemax[w][ct * 16 + lr] = cm;
    }
    __syncthreads();
    if (w == 0) {
      float cm = wavemax[0][lane];
      #pragma unroll
      for (int ww = 1; ww < 8; ++ww) cm = fmaxf(cm, wavemax[ww][lane]);
      colmax[lane] = cm;
      cmax[(size_t)bt0 + lane] = cm;
    }
    __syncthreads();
    #pragma unroll
    for (int ct = 0; ct < 4; ++ct) {
      float cm = colmax[ct * 16 + lr];
      #pragma unroll
      for (int rt = 0; rt < 4; ++rt) {
        float v = expf(lse[rt][ct] - cm);
        if (!(lg & 1))
          ehat[((size_t)bt0 + ct * 16 + lr) * 64 + (w * 8 + rt * 2 + (lg >> 1))] = v;
      }
    }
  }
}

// ---------------- K4: per-chunk product, single fat wave ---------------------
// One 64-lane wave carries the FULL 64-col state as packed bf16; whole
// e-slice staged in LDS up-front (r5); setprio around compute (r4).
__global__ __launch_bounds__(64) void mmm_chunk_kernel(
    const short* __restrict__ WTbf, const float* __restrict__ ehat,
    const float* __restrict__ cmax, float* __restrict__ NT,
    float* __restrict__ aux) {
  __shared__ __align__(16) float elds[1024];  // 16 steps x 64 rows
  int chunk = blockIdx.x, b = blockIdx.y;
  int lane = threadIdx.x;
  int l31 = lane & 31, hi = lane >> 5;

  int t0 = (chunk == 0) ? 1 : chunk * 16;
  int nsteps = (chunk == 0) ? 15 : 16;
  const float* eb = ehat + (size_t)b * 4096 * 64;

  // stage e-slice first (issue-early): rows t0..t0+15 are always in-bounds
  {
    const float* esrc = eb + (size_t)t0 * 64;
    #pragma unroll
    for (int r = 0; r < 4; ++r)
      *(f32x4*)&elds[r * 256 + lane * 4] = *(const f32x4*)&esrc[r * 256 + lane * 4];
  }

  // A = W^T: af[wi][kb], row = wi*32+l31, k = kb*16 + hi*8 + j (shared by strips)
  bf16x8 af[2][4];
  #pragma unroll
  for (int wi = 0; wi < 2; ++wi)
    #pragma unroll
    for (int kb = 0; kb < 4; ++kb)
      af[wi][kb] = *(const bf16x8*)&WTbf[(wi * 32 + l31) * 64 + kb * 16 + hi * 8];

  // packed state: P[s][cm][q][p] = bf16 rows {32cm+8q+4hi+2p, +1} at col s*32+l31
  unsigned P[2][2][4][2];
  #pragma unroll
  for (int s = 0; s < 2; ++s) {
    int col = s * 32 + l31;
    #pragma unroll
    for (int cm = 0; cm < 2; ++cm)
      #pragma unroll
      for (int q = 0; q < 4; ++q)
        #pragma unroll
        for (int p = 0; p < 2; ++p) {
          int row = 32 * cm + 8 * q + 4 * hi + 2 * p;
          unsigned lo = (row == col) ? 0x3F80u : 0u;       // bf16(1.0)
          unsigned h16 = (row + 1 == col) ? 0x3F80u : 0u;
          P[s][cm][q][p] = lo | (h16 << 16);
        }
  }

  __syncthreads();  // e-slice visible wave-wide

  float logscale = 0.f;
  f32x4 ecur[2][4], enxt[2][4];
  #pragma unroll
  for (int cm = 0; cm < 2; ++cm)
    #pragma unroll
    for (int q = 0; q < 4; ++q)
      ecur[cm][q] = *(const f32x4*)&elds[cm * 32 + q * 8 + hi * 4];

  for (int it = 0; it < nsteps; ++it) {
    if (it + 1 < nsteps) {  // prefetch next step's e from LDS
      #pragma unroll
      for (int cm = 0; cm < 2; ++cm)
        #pragma unroll
        for (int q = 0; q < 4; ++q)
          enxt[cm][q] = *(const f32x4*)&elds[(it + 1) * 64 + cm * 32 + q * 8 + hi * 4];
    }

    __builtin_amdgcn_s_setprio(1);
    #pragma unroll
    for (int s = 0; s < 2; ++s) {
      // B[kb]: k = kb*16 + 8*hi + j; one permlane32_swap per (quad-pair, p)
      bf16x8 B[4];
      #pragma unroll
      for (int kb = 0; kb < 4; ++kb) {
        int cm = kb >> 1, kbl = kb & 1;
        int4 wrd;
        #pragma unroll
        for (int p = 0; p < 2; ++p) {
          unsigned avv = P[s][cm][2 * kbl + 1][p];
          unsigned bvv = P[s][cm][2 * kbl][p];
          asm("v_permlane32_swap_b32 %0, %1" : "+v"(avv), "+v"(bvv));
          if (p == 0) { wrd.x = (int)bvv; wrd.z = (int)avv; }
          else        { wrd.y = (int)bvv; wrd.w = (int)avv; }
        }
        B[kb] = *(bf16x8*)&wrd;
      }

      f32x16 d0, d1;
      #pragma unroll
      for (int r = 0; r < 16; ++r) { d0[r] = 0.f; d1[r] = 0.f; }
      #pragma unroll
      for (int kb = 0; kb < 4; ++kb) {
        d0 = mfma32(af[0][kb], B[kb], d0);
        d1 = mfma32(af[1][kb], B[kb], d1);
      }

      // P = pack(d * e): reg 4q+s_ -> row 32cm+8q+4hi+s_
      #pragma unroll
      for (int q = 0; q < 4; ++q)
        #pragma unroll
        for (int p = 0; p < 2; ++p) {
          P[s][0][q][p] = cvtpk(d0[4 * q + 2 * p] * ecur[0][q][2 * p],
                                d0[4 * q + 2 * p + 1] * ecur[0][q][2 * p + 1]);
          P[s][1][q][p] = cvtpk(d1[4 * q + 2 * p] * ecur[1][q][2 * p],
                                d1[4 * q + 2 * p + 1] * ecur[1][q][2 * p + 1]);
        }
    }
    __builtin_amdgcn_s_setprio(0);

    if ((it & 7) == 7) {  // whole-chunk rescale, applied in place on P
      float m = 0.f;
      #pragma unroll
      for (int s = 0; s < 2; ++s)
        #pragma unroll
        for (int cm = 0; cm < 2; ++cm)
          #pragma unroll
          for (int q = 0; q < 4; ++q)
            #pragma unroll
            for (int p = 0; p < 2; ++p) {
              unsigned u = P[s][cm][q][p];
              m = fmaxf(m, __uint_as_float(u << 16));
              m = fmaxf(m, __uint_as_float(u & 0xffff0000u));
            }
      #pragma unroll
      for (int off = 1; off < 64; off <<= 1) m = fmaxf(m, __shfl_xor(m, off));
      float inv = 1.0f / m;
      #pragma unroll
      for (int s = 0; s < 2; ++s)
        #pragma unroll
        for (int cm = 0; cm < 2; ++cm)
          #pragma unroll
          for (int q = 0; q < 4; ++q)
            #pragma unroll
            for (int p = 0; p < 2; ++p) {
              unsigned u = P[s][cm][q][p];
              P[s][cm][q][p] = cvtpk(__uint_as_float(u << 16) * inv,
                                     __uint_as_float(u & 0xffff0000u) * inv);
            }
      logscale += logf(m);
    }

    #pragma unroll
    for (int cm = 0; cm < 2; ++cm)
      #pragma unroll
      for (int q = 0; q < 4; ++q) ecur[cm][q] = enxt[cm][q];
  }

  // store N_c f32 row-major [row][col]
  float* No = NT + (((size_t)b * 256 + chunk) << 12);
  #pragma unroll
  for (int s = 0; s < 2; ++s)
    #pragma unroll
    for (int cm = 0; cm < 2; ++cm)
      #pragma unroll
      for (int q = 0; q < 4; ++q)
        #pragma unroll
        for (int p = 0; p < 2; ++p) {
          int row = 32 * cm + 8 * q + 4 * hi + 2 * p;
          int col = s * 32 + l31;
          unsigned u = P[s][cm][q][p];
          No[row * 64 + col] = __uint_as_float(u << 16);
          No[(row + 1) * 64 + col] = __uint_as_float(u & 0xffff0000u);
        }

  // aux[b][chunk] = sum cmax + chunk logscale (single scale, whole chunk)
  float cs = (lane < nsteps) ? cmax[(size_t)b * 4096 + t0 + lane] : 0.f;
  #pragma unroll
  for (int off = 1; off < 64; off <<= 1) cs += __shfl_xor(cs, off);
  if (lane == 0) aux[(size_t)b * 256 + chunk] = cs + logscale;
}

// ---------------- K5: merge 16 chunks -> group matrix (16 groups/batch) -----
// Q' = N_cc * Q; N_cc uniformly scaled (single aux scalar per chunk).
__global__ __launch_bounds__(256) void mmm_merge_kernel(
    const float* __restrict__ NT, const float* __restrict__ aux,
    float* __restrict__ G2T, float* __restrict__ auxg) {
  int g = blockIdx.x, b = blockIdx.y;
  int tid = threadIdx.x;
  int w = tid >> 6, lane = tid & 63;
  int wi = w >> 1, wj = w & 1;
  int lr = lane & 15, lg = lane >> 4;

  __shared__ __align__(16) short L[2][4096];
  __shared__ float wmax[4];

  for (int idx = tid; idx < 4096; idx += 256) {
    int j = idx >> 6, k = idx & 63;
    L[0][idx ^ ((j & 7) << 3)] = (j == k) ? (short)0x3F80 : (short)0;
  }
  __syncthreads();

  int cbase = b * 256 + g * 16;

  float logscale = 0.f;
  int cur = 0;
  f32x4 acc[2][2];

  f32x4 apre[2][2][2];
  {
    const float* Mc = NT + ((size_t)cbase << 12);
    #pragma unroll
    for (int rt = 0; rt < 2; ++rt)
      #pragma unroll
      for (int kc = 0; kc < 2; ++kc) {
        const float* src = Mc + (wi * 32 + rt * 16 + lr) * 64 + kc * 32 + lg * 8;
        apre[rt][kc][0] = *(const f32x4*)src;
        apre[rt][kc][1] = *(const f32x4*)(src + 4);
      }
  }

  for (int cc = 0; cc < 16; ++cc) {
    f32x4 acur[2][2][2];
    #pragma unroll
    for (int rt = 0; rt < 2; ++rt)
      #pragma unroll
      for (int kc = 0; kc < 2; ++kc) {
        acur[rt][kc][0] = apre[rt][kc][0];
        acur[rt][kc][1] = apre[rt][kc][1];
      }
    if (cc < 15) {
      const float* Mc = NT + ((size_t)(cbase + cc + 1) << 12);
      #pragma unroll
      for (int rt = 0; rt < 2; ++rt)
        #pragma unroll
        for (int kc = 0; kc < 2; ++kc) {
          const float* src = Mc + (wi * 32 + rt * 16 + lr) * 64 + kc * 32 + lg * 8;
          apre[rt][kc][0] = *(const f32x4*)src;
          apre[rt][kc][1] = *(const f32x4*)(src + 4);
        }
    }

    // single scale per chunk: just accumulate the log
    logscale += aux[cbase + cc];

    bf16x8 afr[2][2];
    #pragma unroll
    for (int rt = 0; rt < 2; ++rt)
      #pragma unroll
      for (int kc = 0; kc < 2; ++kc) {
        unsigned fw[4];
        fw[0] = cvtpk(acur[rt][kc][0][0], acur[rt][kc][0][1]);
        fw[1] = cvtpk(acur[rt][kc][0][2], acur[rt][kc][0][3]);
        fw[2] = cvtpk(acur[rt][kc][1][0], acur[rt][kc][1][1]);
        fw[3] = cvtpk(acur[rt][kc][1][2], acur[rt][kc][1][3]);
        afr[rt][kc] = *(bf16x8*)fw;
      }

    bf16x8 bfr[2][2];
    #pragma unroll
    for (int ct = 0; ct < 2; ++ct) {
      int j = wj * 32 + ct * 16 + lr;
      int sw = (j & 7) << 3;
      #pragma unroll
      for (int kc = 0; kc < 2; ++kc)
        bfr[ct][kc] = *(const bf16x8*)&L[cur][(j * 64 + kc * 32 + lg * 8) ^ sw];
    }

    #pragma unroll
    for (int rt = 0; rt < 2; ++rt)
      #pragma unroll
      for (int ct = 0; ct < 2; ++ct) {
        f32x4 c = {0.f, 0.f, 0.f, 0.f};
        c = mfma16(afr[rt][0], bfr[ct][0], c);
        c = mfma16(afr[rt][1], bfr[ct][1], c);
        acc[rt][ct] = c;
      }

    float m = 0.f;
    #pragma unroll
    for (int rt = 0; rt < 2; ++rt)
      #pragma unroll
      for (int ct = 0; ct < 2; ++ct)
        #pragma unroll
        for (int r = 0; r < 4; ++r) m = fmaxf(m, acc[rt][ct][r]);
    #pragma unroll
    for (int off = 1; off < 64; off <<= 1) m = fmaxf(m, __shfl_xor(m, off));
    if (lane == 0) wmax[w] = m;
    __syncthreads();
    m = fmaxf(fmaxf(wmax[0], wmax[1]), fmaxf(wmax[2], wmax[3]));
    float inv = 1.0f / m;
    #pragma unroll
    for (int rt = 0; rt < 2; ++rt)
      #pragma unroll
      for (int ct = 0; ct < 2; ++ct) acc[rt][ct] *= inv;
    logscale += logf(m);

    int nxt = cur ^ 1;
    unsigned* L32 = (unsigned*)&L[nxt][0];
    #pragma unroll
    for (int rt = 0; rt < 2; ++rt)
      #pragma unroll
      for (int ct = 0; ct < 2; ++ct) {
        int row0 = wi * 32 + rt * 16 + lg * 4;   // 4-aligned
        int col = wj * 32 + ct * 16 + lr;
        int sidx = (col * 64 + row0) ^ ((col & 7) << 3);  // XOR hits bits>=3 only
        L32[(sidx >> 1) + 0] = cvtpk(acc[rt][ct][0], acc[rt][ct][1]);
        L32[(sidx >> 1) + 1] = cvtpk(acc[rt][ct][2], acc[rt][ct][3]);
      }
    __syncthreads();
    cur = nxt;
  }

  float* Mo = G2T + (((size_t)b * 16 + g) << 12);
  #pragma unroll
  for (int rt = 0; rt < 2; ++rt)
    #pragma unroll
    for (int ct = 0; ct < 2; ++ct)
      #pragma unroll
      for (int r = 0; r < 4; ++r) {
        int row = wi * 32 + rt * 16 + lg * 4 + r;
        int col = wj * 32 + ct * 16 + lr;
        Mo[row * 64 + col] = acc[rt][ct][r];
      }

  if (w == 0 && lane == 0) auxg[b * 16 + g] = logscale;
}

// ---------------- K6: final combine (16 group matrices per batch) -----------
// r6: double-buffer the G2T slice (issue g+1's loads before g's dot) — with
// only 8 blocks on the chip, the 16 serial cold 16KB reads (~900cy each) were
// fully exposed; prefetch hides them under the reduce+logf chain.
__global__ __launch_bounds__(64) void mmm_combine_kernel(
    const float* __restrict__ pi_logits, const float* __restrict__ ehat,
    const float* __restrict__ cmax, const float* __restrict__ G2T,
    const float* __restrict__ auxg, float* __restrict__ out) {
  int b = blockIdx.x, lane = threadIdx.x;
  __shared__ __align__(16) float alds[64];

  float pv = pi_logits[lane];
  float mx = pv;
  #pragma unroll
  for (int off = 1; off < 64; off <<= 1) mx = fmaxf(mx, __shfl_xor(mx, off));
  float pe = expf(pv - mx);
  float ps = pe;
  #pragma unroll
  for (int off = 1; off < 64; off <<= 1) ps += __shfl_xor(ps, off);

  float a = (pe / ps) * ehat[(size_t)b * 4096 * 64 + lane];
  double logtot = (double)cmax[(size_t)b * 4096];
  alds[lane] = a;
  __builtin_amdgcn_wave_barrier();

  const float* Mb = G2T + (((size_t)b * 16) << 12) + lane * 64;
  f32x4 mc[16], mn[16];
  #pragma unroll
  for (int i = 0; i < 16; ++i) mc[i] = *(const f32x4*)&Mb[i * 4];

  for (int g = 0; g < 16; ++g) {
    if (g < 15) {
      const float* Mn = Mb + ((size_t)(g + 1) << 12);
      #pragma unroll
      for (int i = 0; i < 16; ++i) mn[i] = *(const f32x4*)&Mn[i * 4];
    }
    f32x4 a4 = {0.f, 0.f, 0.f, 0.f};
    #pragma unroll
    for (int i = 0; i < 16; ++i) {
      f32x4 av = *(const f32x4*)&alds[i * 4];
      a4 += mc[i] * av;
    }
    float acc = (a4[0] + a4[1]) + (a4[2] + a4[3]);
    float s = acc;
    #pragma unroll
    for (int off = 1; off < 64; off <<= 1) s += __shfl_xor(s, off);
    logtot += (double)(auxg[b * 16 + g] + logf(s));
    float an = acc / s;
    __builtin_amdgcn_wave_barrier();
    alds[lane] = an;
    __builtin_amdgcn_wave_barrier();
    #pragma unroll
    for (int i = 0; i < 16; ++i) mc[i] = mn[i];
  }
  if (lane == 0) out[b] = (float)logtot;
}

extern "C" void kernel_launch(void* const* d_in, const int* in_sizes, int n_in,
                              void* d_out, int out_size, void* d_ws, size_t ws_size,
                              hipStream_t stream) {
  const float* X      = (const float*)d_in[0];
  const float* pi_l   = (const float*)d_in[1];
  const float* tr_l   = (const float*)d_in[2];
  const float* wl     = (const float*)d_in[3];
  const float* means  = (const float*)d_in[4];
  const float* lvs    = (const float*)d_in[5];
  float* out = (float*)d_out;

  float* ws = (float*)d_ws;
  short* Gt      = (short*)ws;                 // 131072 shorts = 65536 f32
  float* const_c = ws + 65536;                 // 512
  short* WTbf    = (short*)(ws + 66048);       // 4096 shorts = 2048 f32
  float* cmaxp   = ws + 68608;                 // 32768
  float* ehat    = ws + 101376;                // 2097152
  short* XeP     = (short*)(ws + 2198528);     // 16 MB
  float* NT      = ws + 2198528;               // aliases XeP (dead after emis); 8388608 f32
  float* aux     = ws + 10587136;              // 2048 (256 chunks x 8 b)
  float* G2T     = ws + 10591232;              // 524288 (8 b x 16 g x 4096)
  float* auxg    = ws + 11115520;              // 128

  mmm_prep_fused<<<832, 256, 0, stream>>>(tr_l, means, lvs, wl, X,
                                          WTbf, Gt, const_c, XeP);
  mmm_emis_kernel<<<256, 512, 0, stream>>>(Gt, XeP, const_c, ehat, cmaxp);
  mmm_chunk_kernel<<<dim3(256, 8), 64, 0, stream>>>(WTbf, ehat, cmaxp, NT, aux);
  mmm_merge_kernel<<<dim3(16, 8), 256, 0, stream>>>(NT, aux, G2T, auxg);
  mmm_combine_kernel<<<8, 64, 0, stream>>>(pi_l, ehat, cmaxp, G2T, auxg, out);
}